// Round 10
// baseline (548.100 us; speedup 1.0000x reference)
//
#include <hip/hip_runtime.h>
#include <math.h>

#define HW 4096
#define EPSV 1e-5f

typedef _Float16 half8 __attribute__((ext_vector_type(8)));
typedef float f32x4 __attribute__((ext_vector_type(4)));
union H8 { half8 v; ushort4 q[2]; uint4 u4; };

// slab layout (float offsets)
#define SLAB_F 23068672ull
#define OFF_Y1A 0
#define OFF_Y2A 2097152
#define OFF_Y1B 4194304
#define OFF_Y2B 8388608
#define OFF_CCB 12582912
#define OFF_P1  14680064   // 4,194,304 f32; conv1's vbuf aliases here (batched)
#define OFF_P2  18874368   // 4,194,304 f32

// ---------------- bn stats over x: one (b,c) plane per block, float4 ----------------
__global__ __launch_bounds__(256) void bn_partial_kernel(
    const float* __restrict__ x, float* __restrict__ pstat) {
  int c = blockIdx.x, b = blockIdx.y;
  int tid = threadIdx.x;
  const float4* p = (const float4*)(x + ((size_t)b * 64 + c) * HW);
  float sm = 0.f, s2 = 0.f;
  #pragma unroll
  for (int i = 0; i < 4; i++) {
    float4 v = p[tid + i * 256];
    sm += v.x + v.y + v.z + v.w;
    s2 += v.x * v.x + v.y * v.y + v.z * v.z + v.w * v.w;
  }
  __shared__ float sh[2][256];
  sh[0][tid] = sm; sh[1][tid] = s2;
  __syncthreads();
  for (int off = 128; off > 0; off >>= 1) {
    if (tid < off) { sh[0][tid] += sh[0][tid + off]; sh[1][tid] += sh[1][tid + off]; }
    __syncthreads();
  }
  if (tid == 0) {
    pstat[((size_t)b * 64 + c) * 2] = sh[0][0];
    pstat[((size_t)b * 64 + c) * 2 + 1] = sh[1][0];
  }
}

// ---------------- bn stats over v (f16): one (br,b,c) plane per block ----------------
__global__ __launch_bounds__(256) void bnv_partial_kernel(
    const _Float16* __restrict__ vb0, size_t vstrideH, float* __restrict__ pstat) {
  int c = blockIdx.x, b = blockIdx.y, br = blockIdx.z;
  int tid = threadIdx.x;
  const _Float16* row = vb0 + (size_t)br * vstrideH + ((size_t)b * 64 + c) * HW;
  float sm = 0.f, s2 = 0.f;
  #pragma unroll
  for (int i = 0; i < 2; i++) {
    H8 v; v.u4 = *(const uint4*)(row + (tid + i * 256) * 8);
    #pragma unroll
    for (int k = 0; k < 8; k++) { float t = (float)v.v[k]; sm += t; s2 += t * t; }
  }
  __shared__ float sh[2][256];
  sh[0][tid] = sm; sh[1][tid] = s2;
  __syncthreads();
  for (int off = 128; off > 0; off >>= 1) {
    if (tid < off) { sh[0][tid] += sh[0][tid + off]; sh[1][tid] += sh[1][tid + off]; }
    __syncthreads();
  }
  if (tid == 0) {
    pstat[(((size_t)br * 32 + b) * 64 + c) * 2] = sh[0][0];
    pstat[(((size_t)br * 32 + b) * 64 + c) * 2 + 1] = sh[1][0];
  }
}

// ---------------- pack static conv weights into MFMA A-fragment order ----------------
__global__ __launch_bounds__(256) void pack_static_kernel(
    const float* __restrict__ wk1c1, const float* __restrict__ wk1c2,
    const float* __restrict__ wk2c1, const float* __restrict__ wk2c2,
    const float* __restrict__ wconv, _Float16* __restrict__ wpk) {
  int idx = blockIdx.x * 256 + threadIdx.x;  // 258048
  int j = idx & 7, lane = (idx >> 3) & 63;
  int tap = (idx >> 9) % 9;
  int chunk = (idx / 4608) % 14;
  int br = idx / 64512;
  int g = lane >> 4;
  int c = (j < 4) ? 4 * g + j : 16 + 4 * g + (j - 4);
  const float* src; int ol0;
  if (chunk < 2)       { src = wk1c1 + (size_t)br * 32 * 288; ol0 = chunk * 16; }
  else if (chunk < 6)  { src = wk1c2 + (size_t)br * 64 * 288; ol0 = (chunk - 2) * 16; }
  else if (chunk < 8)  { src = wk2c1 + (size_t)br * 32 * 288; ol0 = (chunk - 6) * 16; }
  else if (chunk < 12) { src = wk2c2 + (size_t)br * 64 * 288; ol0 = (chunk - 8) * 16; }
  else                 { src = wconv + (size_t)br * 32 * 288; ol0 = (chunk - 12) * 16; }
  int o = ol0 + (lane & 15);
  wpk[idx] = (_Float16)(src[((size_t)o * 32 + c) * 9 + tap]);
}

// ---------------- MFMA conv: 9 shifted K=32 GEMMs; branch via blockIdx.z ----------------
template <int MODE>
__global__ __launch_bounds__(256) void conv_mfma_kernel(
    const float* __restrict__ xin, const _Float16* __restrict__ wAll,
    const float* __restrict__ pstat, const float* __restrict__ a_pre,
    int brBase, float* __restrict__ slabBase, size_t slabStride,
    _Float16* __restrict__ vb0, size_t vstrideH) {
  const int NCHUNK = (MODE == 0) ? 14 : 4;
  int bz = blockIdx.z;
  int br = brBase + bz;
  float* slab = slabBase + (size_t)bz * slabStride;
  __shared__ _Float16 hsh[6 * 66 * 36];  // [row6][col66][c-pad36]
  __shared__ float alsh[32], besh[32];
  int tid = threadIdx.x;
  int b = blockIdx.y, r0 = blockIdx.x * 4;
  int ch0 = (br & 1) * 32;
  if (MODE == 0 && tid < 32) {  // reduce x-stats + fold bn/shortcut into affine
    float s = 0.f, s2 = 0.f;
    for (int bb = 0; bb < 32; bb++) {
      size_t p = ((size_t)bb * 64 + ch0 + tid) * 2;
      s += pstat[p]; s2 += pstat[p + 1];
    }
    const float N = 131072.f;
    float m = s / N;
    float r = rsqrtf(s2 / N - m * m + EPSV);
    alsh[tid] = 0.5f * r + 0.01f * a_pre[br];
    besh[tid] = -0.5f * m * r;
  }
  __syncthreads();
  for (int t = tid; t < 384; t += 256) {  // zero halo cols
    int row = t >> 6, colh = ((t & 63) >> 5) ? 65 : 0, c = t & 31;
    hsh[(row * 66 + colh) * 36 + c] = (_Float16)0.f;
  }
  if (MODE == 0) {
    for (int t = tid; t < 32 * 96; t += 256) {  // float4 staging + affine
      int c = t / 96, p4 = (t % 96) * 4;
      int row = p4 >> 6, col = p4 & 63;
      int rg = r0 + row - 1;
      float4 v4 = {0.f, 0.f, 0.f, 0.f};
      if ((unsigned)rg < 64u)
        v4 = *(const float4*)&xin[((size_t)b * 64 + ch0 + c) * HW + (rg << 6) + col];
      float a = alsh[c], be = besh[c];
      _Float16* dst = &hsh[((size_t)row * 66 + col + 1) * 36 + c];
      dst[0]   = (_Float16)(v4.x * a + be);
      dst[36]  = (_Float16)(v4.y * a + be);
      dst[72]  = (_Float16)(v4.z * a + be);
      dst[108] = (_Float16)(v4.w * a + be);
    }
  } else {
    const _Float16* cin = (const _Float16*)(slab + OFF_CCB);
    for (int t = tid; t < 32 * 48; t += 256) {  // 16B staging
      int c = t / 48, p8 = (t % 48) * 8;
      int row = p8 >> 6, col = p8 & 63;
      int rg = r0 + row - 1;
      H8 v; v.u4 = make_uint4(0, 0, 0, 0);
      if ((unsigned)rg < 64u)
        v.u4 = *(const uint4*)&cin[((size_t)b * 32 + c) * HW + (rg << 6) + col];
      _Float16* dst = &hsh[((size_t)row * 66 + col + 1) * 36 + c];
      #pragma unroll
      for (int k = 0; k < 8; k++) dst[36 * k] = v.v[k];
    }
  }
  __syncthreads();
  int w = tid >> 6, l = tid & 63;
  int ln = l & 15, g = l >> 4;
  H8 bfr[4][9];
  #pragma unroll
  for (int pf = 0; pf < 4; pf++)
    #pragma unroll
    for (int dyi = 0; dyi < 3; dyi++)
      #pragma unroll
      for (int dxi = 0; dxi < 3; dxi++) {
        const _Float16* p = &hsh[(((size_t)(w + dyi)) * 66 + pf * 16 + ln + dxi) * 36 + 4 * g];
        H8 f;
        f.q[0] = *(const ushort4*)p;
        f.q[1] = *(const ushort4*)(p + 16);
        bfr[pf][dyi * 3 + dxi] = f;
      }
  const _Float16* wb = (MODE == 0)
      ? wAll + (size_t)br * 64512
      : wAll + (size_t)br * 589824 + (size_t)b * 18432;
  for (int chunk = 0; chunk < NCHUNK; chunk++) {
    H8 af[9];
    #pragma unroll
    for (int t = 0; t < 9; t++)
      af[t].u4 = *(const uint4*)(wb + (((size_t)chunk * 9 + t) * 64 + l) * 8);
    _Float16* ob; int Cb, ol0;
    if (MODE == 0) {
      if (chunk < 2)       { ob = (_Float16*)(slab + OFF_Y1A); Cb = 32; ol0 = chunk * 16; }
      else if (chunk < 6)  { ob = (_Float16*)(slab + OFF_Y1B); Cb = 64; ol0 = (chunk - 2) * 16; }
      else if (chunk < 8)  { ob = (_Float16*)(slab + OFF_Y2A); Cb = 32; ol0 = (chunk - 6) * 16; }
      else if (chunk < 12) { ob = (_Float16*)(slab + OFF_Y2B); Cb = 64; ol0 = (chunk - 8) * 16; }
      else                 { ob = (_Float16*)(slab + OFF_CCB); Cb = 32; ol0 = (chunk - 12) * 16; }
    } else { ob = vb0 + (size_t)br * vstrideH; Cb = 64; ol0 = chunk * 16; }
    #pragma unroll
    for (int pf = 0; pf < 4; pf++) {
      f32x4 acc = {0.f, 0.f, 0.f, 0.f};
      #pragma unroll
      for (int t = 0; t < 9; t++)
        acc = __builtin_amdgcn_mfma_f32_16x16x32_f16(bfr[pf][t].v, af[t].v, acc, 0, 0, 0);
      union { _Float16 h[4]; ushort4 u; } sv;
      #pragma unroll
      for (int j = 0; j < 4; j++) sv.h[j] = (_Float16)acc[j];
      int px = ((r0 + w) << 6) + pf * 16 + 4 * g;
      *(ushort4*)&ob[((size_t)b * Cb + ol0 + ln) * HW + px] = sv.u;
    }
  }
}

// ---------------- merged attn partials: attn1 (k=3) + attn2 (k=1) in one launch ----------------
// grid x = 42*nbr + 64*nbr, y = 32
__global__ __launch_bounds__(256) void attn_partial_kernel(
    float* __restrict__ slabBase, size_t slabStride, int nbr) {
  __shared__ float smem[96][65];
  int bx = blockIdx.x, b = blockIdx.y;
  int tid = threadIdx.x;
  int col = tid & 63, rw = tid >> 6;
  int a1x = 42 * nbr;
  if (bx < a1x) {
    // ---- attn1: z = bx/21 in [0,2*nbr), u = bx%21 -> rc,rg ----
    int z = bx / 21, u = bx % 21;
    int rc = u / 7, rg = u % 7;
    int sb = z >> 1, oh = z & 1;
    float* slab = slabBase + (size_t)sb * slabStride;
    const _Float16* y1 = (const _Float16*)(slab + OFF_Y1A);
    const _Float16* y2 = (const _Float16*)(slab + OFF_Y1B);
    float* part = slab + OFF_P1;
    int ol = tid >> 3;
    int i0 = (tid & 7) * 4;
    float acc[4][3] = {};
    const _Float16* y1b = y1 + (size_t)b * 32 * HW;
    const _Float16* y2b = y2 + ((size_t)b * 64 + oh * 32) * HW;
    for (int j = 0; j < 3; j++) {
      int r = rc + 9 * rg + 3 * j;
      __syncthreads();
      for (int c = rw; c < 32; c += 4) {
        smem[c][col]      = (float)(y1b[(size_t)c * HW + (r << 6) + col]);
        smem[32 + c][col] = (float)(y2b[(size_t)c * HW + (r << 6) + col]);
      }
      __syncthreads();
      for (int c3 = 0; c3 < 21; c3++) {
        #pragma unroll
        for (int cc = 0; cc < 3; cc++) {
          int c = 3 * c3 + cc;
          float yo = smem[32 + ol][c];
          #pragma unroll
          for (int ii = 0; ii < 4; ii++) acc[ii][cc] += smem[i0 + ii][c] * yo;
        }
      }
    }
    size_t base = ((((size_t)(rc * 7 + rg) * 32 + b) * 2 + oh) * 3) * 1024 + ol * 32 + i0;
    #pragma unroll
    for (int cc = 0; cc < 3; cc++) {
      float4 v = {acc[0][cc], acc[1][cc], acc[2][cc], acc[3][cc]};
      *(float4*)&part[base + (size_t)cc * 1024] = v;
    }
  } else {
    // ---- attn2: q = bx - a1x -> ps, sb ----
    int q = bx - a1x;
    int ps = q & 63, sb = q >> 6;
    float* slab = slabBase + (size_t)sb * slabStride;
    const _Float16* y1 = (const _Float16*)(slab + OFF_Y2A);
    const _Float16* y2 = (const _Float16*)(slab + OFF_Y2B);
    float* part = slab + OFF_P2;
    int o = tid >> 2, i0 = (tid & 3) * 8;
    const _Float16* y1b = y1 + (size_t)b * 32 * HW + ps * 64;
    const _Float16* y2b = y2 + (size_t)b * 64 * HW + ps * 64;
    for (int c = rw; c < 32; c += 4) smem[c][col] = (float)(y1b[(size_t)c * HW + col]);
    for (int c = rw; c < 64; c += 4) smem[32 + c][col] = (float)(y2b[(size_t)c * HW + col]);
    __syncthreads();
    float acc[8] = {};
    #pragma unroll 8
    for (int p = 0; p < 64; p++) {
      float yo = smem[32 + o][p];
      #pragma unroll
      for (int ii = 0; ii < 8; ii++) acc[ii] += smem[i0 + ii][p] * yo;
    }
    size_t base = ((size_t)ps * 32 + b) * 2048 + o * 32 + i0;
    for (int ii = 0; ii < 8; ii++) part[base + ii] = acc[ii];
  }
}

// ---------------- fused: reduce partials + softmax + ak + pack ----------------
__global__ __launch_bounds__(320) void fused_ak_kernel(
    float* __restrict__ slabBase, size_t slabStride, int brBase,
    const float* __restrict__ aw, _Float16* __restrict__ wdynB) {
  int o = blockIdx.x, b = blockIdx.y;
  int bz = blockIdx.z, br = brBase + bz;
  float* slab = slabBase + (size_t)bz * slabStride;
  const float* part1 = slab + OFF_P1;
  const float* part2 = slab + OFF_P2;
  const float* awb = aw + (size_t)br * 18432;
  _Float16* wdyn = wdynB + (size_t)br * 589824;
  int tid = threadIdx.x;
  __shared__ float sm[33];
  if (tid < 32) {
    float s = 0.f;
    for (int ps = 0; ps < 64; ps++) s += part2[((size_t)ps * 32 + b) * 2048 + o * 32 + tid];
    sm[tid] = s * 0.17677669529663687f;  // 1/sqrt(32)
  }
  __syncthreads();
  if (tid == 0) {
    float mx = -1e30f;
    for (int k = 0; k < 32; k++) mx = fmaxf(mx, sm[k]);
    float sum = 0.f;
    for (int k = 0; k < 32; k++) { float e = expf(sm[k] - mx); sm[k] = e; sum += e; }
    sm[32] = 1.0f / sum;
  }
  __syncthreads();
  if (tid < 288) {
    int i = tid / 9, kk = tid % 9;
    int rc = kk / 3, cc = kk % 3;
    float a1v = 0.f;
    for (int rg = 0; rg < 7; rg++)
      a1v += part1[((((size_t)(rc * 7 + rg) * 32 + b) * 2 + (o >> 5)) * 3 + cc) * 1024 +
                   (o & 31) * 32 + i];
    a1v *= 0.05892556509887896f;  // 1/sqrt(288)
    float akv = sm[i] * sm[32] * (a1v + awb[(size_t)(o * 32 + i) * 9 + kk]);
    int chunk = o >> 4;
    int g = (i & 15) >> 2;
    int j = (i & 3) + ((i >= 16) ? 4 : 0);
    int lane = (g << 4) | (o & 15);
    wdyn[((((size_t)b * 4 + chunk) * 9 + kk) * 64 + lane) * 8 + j] = (_Float16)akv;
  }
}

// ---------------- fused finalize: v-stats reduce + 4-branch combine ----------------
__global__ __launch_bounds__(256) void finalize_kernel(
    const _Float16* __restrict__ vb0, size_t vstrideH,
    const float* __restrict__ pstat, const float* __restrict__ a_post,
    const float* __restrict__ x, const float* __restrict__ cm,
    float* __restrict__ out) {
  __shared__ float sga[256], sgb[256];
  int t = threadIdx.x;
  {
    int br = t >> 6, o = t & 63;
    float s = 0.f, s2 = 0.f;
    for (int bb = 0; bb < 32; bb++) {
      size_t p = (((size_t)br * 32 + bb) * 64 + o) * 2;
      s += pstat[p]; s2 += pstat[p + 1];
    }
    const float N = 131072.f;
    float m = s / N;
    float r = rsqrtf(s2 / N - m * m + EPSV);
    sga[t] = 0.5f * r + 0.6f * a_post[br];
    sgb[t] = -0.5f * m * r;
  }
  __syncthreads();
  size_t g8 = ((size_t)blockIdx.x * 256 + threadIdx.x) * 8;
  int o = (int)((g8 >> 12) & 63);
  float acc[8], ysv[8];
  #pragma unroll
  for (int br = 0; br < 4; br++) {
    float ga = sga[br * 64 + o], gb = sgb[br * 64 + o];
    H8 v; v.u4 = *(const uint4*)(vb0 + (size_t)br * vstrideH + g8);
    #pragma unroll
    for (int j = 0; j < 8; j++) {
      float y = ga * (float)v.v[j] + gb;
      if (br == 0) acc[j] = y;
      else if (br == 1) acc[j] += y;
      else if (br == 2) ysv[j] = y;
      else acc[j] += ysv[j] * y;
    }
  }
  float cmv = 0.99f * cm[0];
  const float4* xp = (const float4*)(x + g8);
  float4 x0 = xp[0], x1 = xp[1];
  float4 o0, o1;
  o0.x = cmv * x0.x + acc[0] * 0.5773502691896258f;
  o0.y = cmv * x0.y + acc[1] * 0.5773502691896258f;
  o0.z = cmv * x0.z + acc[2] * 0.5773502691896258f;
  o0.w = cmv * x0.w + acc[3] * 0.5773502691896258f;
  o1.x = cmv * x1.x + acc[4] * 0.5773502691896258f;
  o1.y = cmv * x1.y + acc[5] * 0.5773502691896258f;
  o1.z = cmv * x1.z + acc[6] * 0.5773502691896258f;
  o1.w = cmv * x1.w + acc[7] * 0.5773502691896258f;
  float4* op = (float4*)(out + g8);
  op[0] = o0;
  op[1] = o1;
}

extern "C" void kernel_launch(void* const* d_in, const int* in_sizes, int n_in,
                              void* d_out, int out_size, void* d_ws, size_t ws_size,
                              hipStream_t stream) {
  const float* x      = (const float*)d_in[0];
  const float* wk1c1  = (const float*)d_in[1];
  const float* wk1c2  = (const float*)d_in[2];
  const float* wk2c1  = (const float*)d_in[3];
  const float* wk2c2  = (const float*)d_in[4];
  const float* wconv  = (const float*)d_in[5];
  const float* attn_w = (const float*)d_in[6];
  const float* a_pre  = (const float*)d_in[7];
  const float* a_post = (const float*)d_in[8];
  const float* cm     = (const float*)d_in[9];
  float* out = (float*)d_out;

  const size_t FIX_F = 129024ull + 1179648ull + 16384ull;  // wpk + wdyn + pstat
  const size_t needB = (4 * SLAB_F + FIX_F) * 4;
  bool batched = ws_size >= needB;
  size_t nslab = batched ? 4 : 1;

  float* ws = (float*)d_ws;
  float* slab0 = ws;
  float* fixF  = ws + nslab * SLAB_F;
  _Float16* wpk   = (_Float16*)fixF;
  _Float16* wdynB = (_Float16*)(fixF + 129024);
  float* pstat    = fixF + 129024 + 1179648;
  // vbuf: batched -> aliases OFF_P1 in each slab; sequential -> separate region
  _Float16* vb0;
  size_t vstrideH;
  if (batched) { vb0 = (_Float16*)(slab0 + OFF_P1); vstrideH = SLAB_F * 2; }
  else         { vb0 = (_Float16*)(fixF + FIX_F);   vstrideH = 8388608; }

  size_t SS = batched ? SLAB_F : 0;

  bn_partial_kernel<<<dim3(64, 32), 256, 0, stream>>>(x, pstat);
  pack_static_kernel<<<1008, 256, 0, stream>>>(wk1c1, wk1c2, wk2c1, wk2c2, wconv, wpk);

  if (batched) {
    conv_mfma_kernel<0><<<dim3(16, 32, 4), 256, 0, stream>>>(
        x, wpk, pstat, a_pre, 0, slab0, SS, nullptr, 0);
    attn_partial_kernel<<<dim3(424, 32), 256, 0, stream>>>(slab0, SS, 4);
    fused_ak_kernel<<<dim3(64, 32, 4), 320, 0, stream>>>(slab0, SS, 0, attn_w, wdynB);
    conv_mfma_kernel<1><<<dim3(16, 32, 4), 256, 0, stream>>>(
        nullptr, wdynB, nullptr, nullptr, 0, slab0, SS, vb0, vstrideH);
  } else {
    for (int br = 0; br < 4; br++) {
      conv_mfma_kernel<0><<<dim3(16, 32, 1), 256, 0, stream>>>(
          x, wpk, pstat, a_pre, br, slab0, 0, nullptr, 0);
      attn_partial_kernel<<<dim3(106, 32), 256, 0, stream>>>(slab0, 0, 1);
      fused_ak_kernel<<<dim3(64, 32, 1), 320, 0, stream>>>(slab0, 0, br, attn_w, wdynB);
      conv_mfma_kernel<1><<<dim3(16, 32, 1), 256, 0, stream>>>(
          nullptr, wdynB, nullptr, nullptr, br, slab0, 0, vb0, vstrideH);
    }
  }

  bnv_partial_kernel<<<dim3(64, 32, 4), 256, 0, stream>>>(vb0, vstrideH, pstat);
  finalize_kernel<<<4096, 256, 0, stream>>>(vb0, vstrideH, pstat, a_post, x, cm, out);
}

// Round 11
// 514.271 us; speedup vs baseline: 1.0658x; 1.0658x over previous
//
#include <hip/hip_runtime.h>
#include <math.h>

#define HW 4096
#define EPSV 1e-5f

typedef _Float16 half8 __attribute__((ext_vector_type(8)));
typedef float f32x4 __attribute__((ext_vector_type(4)));
union H8 { half8 v; ushort4 q[2]; uint4 u4; };

// slab layout (float offsets)
#define SLAB_F 23068672ull
#define OFF_Y1A 0
#define OFF_Y2A 2097152
#define OFF_Y1B 4194304
#define OFF_Y2B 8388608
#define OFF_CCB 12582912
#define OFF_P1  14680064   // a1 full [b][kk][o][i] (589824 f32); conv1's vbuf aliases here later
#define OFF_P2  18874368   // part2 [ps8][b][o*32+i] (524288 f32)

// ---------------- bn stats over x: one (b,c) plane per block, float4 ----------------
__global__ __launch_bounds__(256) void bn_partial_kernel(
    const float* __restrict__ x, float* __restrict__ pstat) {
  int c = blockIdx.x, b = blockIdx.y;
  int tid = threadIdx.x;
  const float4* p = (const float4*)(x + ((size_t)b * 64 + c) * HW);
  float sm = 0.f, s2 = 0.f;
  #pragma unroll
  for (int i = 0; i < 4; i++) {
    float4 v = p[tid + i * 256];
    sm += v.x + v.y + v.z + v.w;
    s2 += v.x * v.x + v.y * v.y + v.z * v.z + v.w * v.w;
  }
  __shared__ float sh[2][256];
  sh[0][tid] = sm; sh[1][tid] = s2;
  __syncthreads();
  for (int off = 128; off > 0; off >>= 1) {
    if (tid < off) { sh[0][tid] += sh[0][tid + off]; sh[1][tid] += sh[1][tid + off]; }
    __syncthreads();
  }
  if (tid == 0) {
    pstat[((size_t)b * 64 + c) * 2] = sh[0][0];
    pstat[((size_t)b * 64 + c) * 2 + 1] = sh[1][0];
  }
}

// ---------------- bn stats over v (f16): one (br,b,c) plane per block ----------------
__global__ __launch_bounds__(256) void bnv_partial_kernel(
    const _Float16* __restrict__ vb0, size_t vstrideH, float* __restrict__ pstat) {
  int c = blockIdx.x, b = blockIdx.y, br = blockIdx.z;
  int tid = threadIdx.x;
  const _Float16* row = vb0 + (size_t)br * vstrideH + ((size_t)b * 64 + c) * HW;
  float sm = 0.f, s2 = 0.f;
  #pragma unroll
  for (int i = 0; i < 2; i++) {
    H8 v; v.u4 = *(const uint4*)(row + (tid + i * 256) * 8);
    #pragma unroll
    for (int k = 0; k < 8; k++) { float t = (float)v.v[k]; sm += t; s2 += t * t; }
  }
  __shared__ float sh[2][256];
  sh[0][tid] = sm; sh[1][tid] = s2;
  __syncthreads();
  for (int off = 128; off > 0; off >>= 1) {
    if (tid < off) { sh[0][tid] += sh[0][tid + off]; sh[1][tid] += sh[1][tid + off]; }
    __syncthreads();
  }
  if (tid == 0) {
    pstat[(((size_t)br * 32 + b) * 64 + c) * 2] = sh[0][0];
    pstat[(((size_t)br * 32 + b) * 64 + c) * 2 + 1] = sh[1][0];
  }
}

// ---------------- pack static conv weights into MFMA A-fragment order ----------------
__global__ __launch_bounds__(256) void pack_static_kernel(
    const float* __restrict__ wk1c1, const float* __restrict__ wk1c2,
    const float* __restrict__ wk2c1, const float* __restrict__ wk2c2,
    const float* __restrict__ wconv, _Float16* __restrict__ wpk) {
  int idx = blockIdx.x * 256 + threadIdx.x;  // 258048
  int j = idx & 7, lane = (idx >> 3) & 63;
  int tap = (idx >> 9) % 9;
  int chunk = (idx / 4608) % 14;
  int br = idx / 64512;
  int g = lane >> 4;
  int c = (j < 4) ? 4 * g + j : 16 + 4 * g + (j - 4);
  const float* src; int ol0;
  if (chunk < 2)       { src = wk1c1 + (size_t)br * 32 * 288; ol0 = chunk * 16; }
  else if (chunk < 6)  { src = wk1c2 + (size_t)br * 64 * 288; ol0 = (chunk - 2) * 16; }
  else if (chunk < 8)  { src = wk2c1 + (size_t)br * 32 * 288; ol0 = (chunk - 6) * 16; }
  else if (chunk < 12) { src = wk2c2 + (size_t)br * 64 * 288; ol0 = (chunk - 8) * 16; }
  else                 { src = wconv + (size_t)br * 32 * 288; ol0 = (chunk - 12) * 16; }
  int o = ol0 + (lane & 15);
  wpk[idx] = (_Float16)(src[((size_t)o * 32 + c) * 9 + tap]);
}

// ---------------- MFMA conv: 9 shifted K=32 GEMMs; branch via blockIdx.z ----------------
template <int MODE>
__global__ __launch_bounds__(256) void conv_mfma_kernel(
    const float* __restrict__ xin, const _Float16* __restrict__ wAll,
    const float* __restrict__ pstat, const float* __restrict__ a_pre,
    int brBase, float* __restrict__ slabBase, size_t slabStride,
    _Float16* __restrict__ vb0, size_t vstrideH) {
  const int NCHUNK = (MODE == 0) ? 14 : 4;
  int bz = blockIdx.z;
  int br = brBase + bz;
  float* slab = slabBase + (size_t)bz * slabStride;
  __shared__ _Float16 hsh[6 * 66 * 36];  // [row6][col66][c-pad36]
  __shared__ float alsh[32], besh[32];
  int tid = threadIdx.x;
  int b = blockIdx.y, r0 = blockIdx.x * 4;
  int ch0 = (br & 1) * 32;
  if (MODE == 0 && tid < 32) {  // reduce x-stats + fold bn/shortcut into affine
    float s = 0.f, s2 = 0.f;
    for (int bb = 0; bb < 32; bb++) {
      size_t p = ((size_t)bb * 64 + ch0 + tid) * 2;
      s += pstat[p]; s2 += pstat[p + 1];
    }
    const float N = 131072.f;
    float m = s / N;
    float r = rsqrtf(s2 / N - m * m + EPSV);
    alsh[tid] = 0.5f * r + 0.01f * a_pre[br];
    besh[tid] = -0.5f * m * r;
  }
  __syncthreads();
  for (int t = tid; t < 384; t += 256) {  // zero halo cols
    int row = t >> 6, colh = ((t & 63) >> 5) ? 65 : 0, c = t & 31;
    hsh[(row * 66 + colh) * 36 + c] = (_Float16)0.f;
  }
  if (MODE == 0) {
    for (int t = tid; t < 32 * 96; t += 256) {  // float4 staging + affine
      int c = t / 96, p4 = (t % 96) * 4;
      int row = p4 >> 6, col = p4 & 63;
      int rg = r0 + row - 1;
      float4 v4 = {0.f, 0.f, 0.f, 0.f};
      if ((unsigned)rg < 64u)
        v4 = *(const float4*)&xin[((size_t)b * 64 + ch0 + c) * HW + (rg << 6) + col];
      float a = alsh[c], be = besh[c];
      _Float16* dst = &hsh[((size_t)row * 66 + col + 1) * 36 + c];
      dst[0]   = (_Float16)(v4.x * a + be);
      dst[36]  = (_Float16)(v4.y * a + be);
      dst[72]  = (_Float16)(v4.z * a + be);
      dst[108] = (_Float16)(v4.w * a + be);
    }
  } else {
    const _Float16* cin = (const _Float16*)(slab + OFF_CCB);
    for (int t = tid; t < 32 * 48; t += 256) {  // 16B staging
      int c = t / 48, p8 = (t % 48) * 8;
      int row = p8 >> 6, col = p8 & 63;
      int rg = r0 + row - 1;
      H8 v; v.u4 = make_uint4(0, 0, 0, 0);
      if ((unsigned)rg < 64u)
        v.u4 = *(const uint4*)&cin[((size_t)b * 32 + c) * HW + (rg << 6) + col];
      _Float16* dst = &hsh[((size_t)row * 66 + col + 1) * 36 + c];
      #pragma unroll
      for (int k = 0; k < 8; k++) dst[36 * k] = v.v[k];
    }
  }
  __syncthreads();
  int w = tid >> 6, l = tid & 63;
  int ln = l & 15, g = l >> 4;
  H8 bfr[4][9];
  #pragma unroll
  for (int pf = 0; pf < 4; pf++)
    #pragma unroll
    for (int dyi = 0; dyi < 3; dyi++)
      #pragma unroll
      for (int dxi = 0; dxi < 3; dxi++) {
        const _Float16* p = &hsh[(((size_t)(w + dyi)) * 66 + pf * 16 + ln + dxi) * 36 + 4 * g];
        H8 f;
        f.q[0] = *(const ushort4*)p;
        f.q[1] = *(const ushort4*)(p + 16);
        bfr[pf][dyi * 3 + dxi] = f;
      }
  const _Float16* wb = (MODE == 0)
      ? wAll + (size_t)br * 64512
      : wAll + (size_t)br * 589824 + (size_t)b * 18432;
  for (int chunk = 0; chunk < NCHUNK; chunk++) {
    H8 af[9];
    #pragma unroll
    for (int t = 0; t < 9; t++)
      af[t].u4 = *(const uint4*)(wb + (((size_t)chunk * 9 + t) * 64 + l) * 8);
    _Float16* ob; int Cb, ol0;
    if (MODE == 0) {
      if (chunk < 2)       { ob = (_Float16*)(slab + OFF_Y1A); Cb = 32; ol0 = chunk * 16; }
      else if (chunk < 6)  { ob = (_Float16*)(slab + OFF_Y1B); Cb = 64; ol0 = (chunk - 2) * 16; }
      else if (chunk < 8)  { ob = (_Float16*)(slab + OFF_Y2A); Cb = 32; ol0 = (chunk - 6) * 16; }
      else if (chunk < 12) { ob = (_Float16*)(slab + OFF_Y2B); Cb = 64; ol0 = (chunk - 8) * 16; }
      else                 { ob = (_Float16*)(slab + OFF_CCB); Cb = 32; ol0 = (chunk - 12) * 16; }
    } else { ob = vb0 + (size_t)br * vstrideH; Cb = 64; ol0 = chunk * 16; }
    #pragma unroll
    for (int pf = 0; pf < 4; pf++) {
      f32x4 acc = {0.f, 0.f, 0.f, 0.f};
      #pragma unroll
      for (int t = 0; t < 9; t++)
        acc = __builtin_amdgcn_mfma_f32_16x16x32_f16(bfr[pf][t].v, af[t].v, acc, 0, 0, 0);
      union { _Float16 h[4]; ushort4 u; } sv;
      #pragma unroll
      for (int j = 0; j < 4; j++) sv.h[j] = (_Float16)acc[j];
      int px = ((r0 + w) << 6) + pf * 16 + 4 * g;
      *(ushort4*)&ob[((size_t)b * Cb + ol0 + ln) * HW + px] = sv.u;
    }
  }
}

// ---------------- MFMA attention: bx<9 -> attn1 GEMM (kk=bx, K=448); bx>=9 -> attn2 split-K ----------------
// grid (17, 32, nslab). Per wave: one 16-o chunk x two 16-i tiles.
__global__ __launch_bounds__(256) void attn_mfma_kernel(
    float* __restrict__ slabBase, size_t slabStride) {
  __shared__ _Float16 s1[32][36];
  __shared__ _Float16 s2[64][36];
  int bx = blockIdx.x, b = blockIdx.y;
  float* slab = slabBase + (size_t)blockIdx.z * slabStride;
  int tid = threadIdx.x;
  bool isA1 = bx < 9;
  int di = bx / 3, dj = bx - 3 * (bx / 3);     // attn1 only
  int ps = bx - 9;                              // attn2 only
  const _Float16* y1 = (const _Float16*)(slab + (isA1 ? OFF_Y1A : OFF_Y2A));
  const _Float16* y2 = (const _Float16*)(slab + (isA1 ? OFF_Y1B : OFF_Y2B));
  int w = tid >> 6, lr = tid & 15, g = (tid >> 4) & 3;
  f32x4 acc0 = {0.f, 0.f, 0.f, 0.f}, acc1 = {0.f, 0.f, 0.f, 0.f};
  int NST = isA1 ? 14 : 16;
  for (int kb = 0; kb < NST; kb++) {
    __syncthreads();
    #pragma unroll
    for (int r = 0; r < 12; r++) {
      int idx = tid + 256 * r;     // 0..3071
      int ch = idx >> 5, l = idx & 31;
      int L = kb * 32 + l;
      _Float16 val = (_Float16)0.f;
      if (isA1) {
        if (L < 441) {
          int p = L / 21, q = L - p * 21;
          int px = ((3 * p + di) << 6) + 3 * q + dj;
          val = (ch < 32) ? y1[((size_t)b * 32 + ch) * HW + px]
                          : y2[((size_t)b * 64 + (ch - 32)) * HW + px];
        }
      } else {
        int px = ps * 512 + L;
        val = (ch < 32) ? y1[((size_t)b * 32 + ch) * HW + px]
                        : y2[((size_t)b * 64 + (ch - 32)) * HW + px];
      }
      if (ch < 32) s1[ch][l] = val; else s2[ch - 32][l] = val;
    }
    __syncthreads();
    H8 af, bf0, bf1;
    const _Float16* pa = &s2[16 * w + lr][4 * g];
    af.q[0] = *(const ushort4*)pa;  af.q[1] = *(const ushort4*)(pa + 16);
    const _Float16* pb0 = &s1[lr][4 * g];
    bf0.q[0] = *(const ushort4*)pb0; bf0.q[1] = *(const ushort4*)(pb0 + 16);
    const _Float16* pb1 = &s1[16 + lr][4 * g];
    bf1.q[0] = *(const ushort4*)pb1; bf1.q[1] = *(const ushort4*)(pb1 + 16);
    acc0 = __builtin_amdgcn_mfma_f32_16x16x32_f16(af.v, bf0.v, acc0, 0, 0, 0);
    acc1 = __builtin_amdgcn_mfma_f32_16x16x32_f16(af.v, bf1.v, acc1, 0, 0, 0);
  }
  // D: col=lane&15 -> i, row=4g+j -> o (within 16-chunk); wave w owns o-chunk 16w
  if (isA1) {
    float* a1 = slab + OFF_P1;   // [b][kk][o][i]
    size_t base = (((size_t)b * 9 + bx) * 64 + 16 * w + 4 * g) * 32 + lr;
    #pragma unroll
    for (int j = 0; j < 4; j++) {
      a1[base + (size_t)j * 32] = acc0[j];
      a1[base + (size_t)j * 32 + 16] = acc1[j];
    }
  } else {
    float* p2 = slab + OFF_P2;   // [ps][b][o*32+i]
    size_t base = ((size_t)ps * 32 + b) * 2048 + (16 * w + 4 * g) * 32 + lr;
    #pragma unroll
    for (int j = 0; j < 4; j++) {
      p2[base + (size_t)j * 32] = acc0[j];
      p2[base + (size_t)j * 32 + 16] = acc1[j];
    }
  }
}

// ---------------- fused: reduce attn2 partials + softmax + ak + pack ----------------
__global__ __launch_bounds__(320) void fused_ak_kernel(
    float* __restrict__ slabBase, size_t slabStride, int brBase,
    const float* __restrict__ aw, _Float16* __restrict__ wdynB) {
  int o = blockIdx.x, b = blockIdx.y;
  int bz = blockIdx.z, br = brBase + bz;
  float* slab = slabBase + (size_t)bz * slabStride;
  const float* a1 = slab + OFF_P1;
  const float* part2 = slab + OFF_P2;
  const float* awb = aw + (size_t)br * 18432;
  _Float16* wdyn = wdynB + (size_t)br * 589824;
  int tid = threadIdx.x;
  __shared__ float sm[33];
  if (tid < 32) {
    float s = 0.f;
    #pragma unroll
    for (int ps = 0; ps < 8; ps++) s += part2[((size_t)ps * 32 + b) * 2048 + o * 32 + tid];
    sm[tid] = s * 0.17677669529663687f;  // 1/sqrt(32)
  }
  __syncthreads();
  if (tid == 0) {
    float mx = -1e30f;
    for (int k = 0; k < 32; k++) mx = fmaxf(mx, sm[k]);
    float sum = 0.f;
    for (int k = 0; k < 32; k++) { float e = expf(sm[k] - mx); sm[k] = e; sum += e; }
    sm[32] = 1.0f / sum;
  }
  __syncthreads();
  if (tid < 288) {
    int i = tid / 9, kk = tid % 9;
    float a1v = a1[(((size_t)b * 9 + kk) * 64 + o) * 32 + i] * 0.05892556509887896f;
    float akv = sm[i] * sm[32] * (a1v + awb[(size_t)(o * 32 + i) * 9 + kk]);
    int chunk = o >> 4;
    int g = (i & 15) >> 2;
    int j = (i & 3) + ((i >= 16) ? 4 : 0);
    int lane = (g << 4) | (o & 15);
    wdyn[((((size_t)b * 4 + chunk) * 9 + kk) * 64 + lane) * 8 + j] = (_Float16)akv;
  }
}

// ---------------- fused finalize: v-stats reduce + 4-branch combine ----------------
__global__ __launch_bounds__(256) void finalize_kernel(
    const _Float16* __restrict__ vb0, size_t vstrideH,
    const float* __restrict__ pstat, const float* __restrict__ a_post,
    const float* __restrict__ x, const float* __restrict__ cm,
    float* __restrict__ out) {
  __shared__ float sga[256], sgb[256];
  int t = threadIdx.x;
  {
    int br = t >> 6, o = t & 63;
    float s = 0.f, s2 = 0.f;
    for (int bb = 0; bb < 32; bb++) {
      size_t p = (((size_t)br * 32 + bb) * 64 + o) * 2;
      s += pstat[p]; s2 += pstat[p + 1];
    }
    const float N = 131072.f;
    float m = s / N;
    float r = rsqrtf(s2 / N - m * m + EPSV);
    sga[t] = 0.5f * r + 0.6f * a_post[br];
    sgb[t] = -0.5f * m * r;
  }
  __syncthreads();
  size_t g8 = ((size_t)blockIdx.x * 256 + threadIdx.x) * 8;
  int o = (int)((g8 >> 12) & 63);
  float acc[8], ysv[8];
  #pragma unroll
  for (int br = 0; br < 4; br++) {
    float ga = sga[br * 64 + o], gb = sgb[br * 64 + o];
    H8 v; v.u4 = *(const uint4*)(vb0 + (size_t)br * vstrideH + g8);
    #pragma unroll
    for (int j = 0; j < 8; j++) {
      float y = ga * (float)v.v[j] + gb;
      if (br == 0) acc[j] = y;
      else if (br == 1) acc[j] += y;
      else if (br == 2) ysv[j] = y;
      else acc[j] += ysv[j] * y;
    }
  }
  float cmv = 0.99f * cm[0];
  const float4* xp = (const float4*)(x + g8);
  float4 x0 = xp[0], x1 = xp[1];
  float4 o0, o1;
  o0.x = cmv * x0.x + acc[0] * 0.5773502691896258f;
  o0.y = cmv * x0.y + acc[1] * 0.5773502691896258f;
  o0.z = cmv * x0.z + acc[2] * 0.5773502691896258f;
  o0.w = cmv * x0.w + acc[3] * 0.5773502691896258f;
  o1.x = cmv * x1.x + acc[4] * 0.5773502691896258f;
  o1.y = cmv * x1.y + acc[5] * 0.5773502691896258f;
  o1.z = cmv * x1.z + acc[6] * 0.5773502691896258f;
  o1.w = cmv * x1.w + acc[7] * 0.5773502691896258f;
  float4* op = (float4*)(out + g8);
  op[0] = o0;
  op[1] = o1;
}

extern "C" void kernel_launch(void* const* d_in, const int* in_sizes, int n_in,
                              void* d_out, int out_size, void* d_ws, size_t ws_size,
                              hipStream_t stream) {
  const float* x      = (const float*)d_in[0];
  const float* wk1c1  = (const float*)d_in[1];
  const float* wk1c2  = (const float*)d_in[2];
  const float* wk2c1  = (const float*)d_in[3];
  const float* wk2c2  = (const float*)d_in[4];
  const float* wconv  = (const float*)d_in[5];
  const float* attn_w = (const float*)d_in[6];
  const float* a_pre  = (const float*)d_in[7];
  const float* a_post = (const float*)d_in[8];
  const float* cm     = (const float*)d_in[9];
  float* out = (float*)d_out;

  const size_t FIX_F = 129024ull + 1179648ull + 16384ull;  // wpk + wdyn + pstat
  const size_t needB = (4 * SLAB_F + FIX_F) * 4;
  bool batched = ws_size >= needB;
  size_t nslab = batched ? 4 : 1;

  float* ws = (float*)d_ws;
  float* slab0 = ws;
  float* fixF  = ws + nslab * SLAB_F;
  _Float16* wpk   = (_Float16*)fixF;
  _Float16* wdynB = (_Float16*)(fixF + 129024);
  float* pstat    = fixF + 129024 + 1179648;
  _Float16* vb0;
  size_t vstrideH;
  if (batched) { vb0 = (_Float16*)(slab0 + OFF_P1); vstrideH = SLAB_F * 2; }
  else         { vb0 = (_Float16*)(fixF + FIX_F);   vstrideH = 8388608; }

  size_t SS = batched ? SLAB_F : 0;

  bn_partial_kernel<<<dim3(64, 32), 256, 0, stream>>>(x, pstat);
  pack_static_kernel<<<1008, 256, 0, stream>>>(wk1c1, wk1c2, wk2c1, wk2c2, wconv, wpk);

  if (batched) {
    conv_mfma_kernel<0><<<dim3(16, 32, 4), 256, 0, stream>>>(
        x, wpk, pstat, a_pre, 0, slab0, SS, nullptr, 0);
    attn_mfma_kernel<<<dim3(17, 32, 4), 256, 0, stream>>>(slab0, SS);
    fused_ak_kernel<<<dim3(64, 32, 4), 320, 0, stream>>>(slab0, SS, 0, attn_w, wdynB);
    conv_mfma_kernel<1><<<dim3(16, 32, 4), 256, 0, stream>>>(
        nullptr, wdynB, nullptr, nullptr, 0, slab0, SS, vb0, vstrideH);
  } else {
    for (int br = 0; br < 4; br++) {
      conv_mfma_kernel<0><<<dim3(16, 32, 1), 256, 0, stream>>>(
          x, wpk, pstat, a_pre, br, slab0, 0, nullptr, 0);
      attn_mfma_kernel<<<dim3(17, 32, 1), 256, 0, stream>>>(slab0, 0);
      fused_ak_kernel<<<dim3(64, 32, 1), 320, 0, stream>>>(slab0, 0, br, attn_w, wdynB);
      conv_mfma_kernel<1><<<dim3(16, 32, 1), 256, 0, stream>>>(
          nullptr, wdynB, nullptr, nullptr, br, slab0, 0, vb0, vstrideH);
    }
  }

  bnv_partial_kernel<<<dim3(64, 32, 4), 256, 0, stream>>>(vb0, vstrideH, pstat);
  finalize_kernel<<<4096, 256, 0, stream>>>(vb0, vstrideH, pstat, a_post, x, cm, out);
}

// Round 12
// 440.660 us; speedup vs baseline: 1.2438x; 1.1670x over previous
//
#include <hip/hip_runtime.h>
#include <math.h>

#define HW 4096
#define EPSV 1e-5f

typedef _Float16 half8 __attribute__((ext_vector_type(8)));
typedef float f32x4 __attribute__((ext_vector_type(4)));
union H8 { half8 v; ushort4 q[2]; uint4 u4; };

// slab layout (float offsets)
#define SLAB_F 23068672ull
#define OFF_Y1A 0
#define OFF_Y2A 2097152
#define OFF_Y1B 4194304
#define OFF_Y2B 8388608
#define OFF_CCB 12582912
#define OFF_P1  14680064   // a1 partials [rg7][b][kk][o][i] (4,128,768 f32); conv1 vbuf aliases later
#define OFF_P2  18874368   // part2 [ps8][b][o*32+i] (524288 f32)

// ---------------- bn stats over x: one (b,c) plane per block, float4 ----------------
__global__ __launch_bounds__(256) void bn_partial_kernel(
    const float* __restrict__ x, float* __restrict__ pstat) {
  int c = blockIdx.x, b = blockIdx.y;
  int tid = threadIdx.x;
  const float4* p = (const float4*)(x + ((size_t)b * 64 + c) * HW);
  float sm = 0.f, s2 = 0.f;
  #pragma unroll
  for (int i = 0; i < 4; i++) {
    float4 v = p[tid + i * 256];
    sm += v.x + v.y + v.z + v.w;
    s2 += v.x * v.x + v.y * v.y + v.z * v.z + v.w * v.w;
  }
  __shared__ float sh[2][256];
  sh[0][tid] = sm; sh[1][tid] = s2;
  __syncthreads();
  for (int off = 128; off > 0; off >>= 1) {
    if (tid < off) { sh[0][tid] += sh[0][tid + off]; sh[1][tid] += sh[1][tid + off]; }
    __syncthreads();
  }
  if (tid == 0) {
    pstat[((size_t)b * 64 + c) * 2] = sh[0][0];
    pstat[((size_t)b * 64 + c) * 2 + 1] = sh[1][0];
  }
}

// ---------------- bn stats over v (f16): one (br,b,c) plane per block ----------------
__global__ __launch_bounds__(256) void bnv_partial_kernel(
    const _Float16* __restrict__ vb0, size_t vstrideH, float* __restrict__ pstat) {
  int c = blockIdx.x, b = blockIdx.y, br = blockIdx.z;
  int tid = threadIdx.x;
  const _Float16* row = vb0 + (size_t)br * vstrideH + ((size_t)b * 64 + c) * HW;
  float sm = 0.f, s2 = 0.f;
  #pragma unroll
  for (int i = 0; i < 2; i++) {
    H8 v; v.u4 = *(const uint4*)(row + (tid + i * 256) * 8);
    #pragma unroll
    for (int k = 0; k < 8; k++) { float t = (float)v.v[k]; sm += t; s2 += t * t; }
  }
  __shared__ float sh[2][256];
  sh[0][tid] = sm; sh[1][tid] = s2;
  __syncthreads();
  for (int off = 128; off > 0; off >>= 1) {
    if (tid < off) { sh[0][tid] += sh[0][tid + off]; sh[1][tid] += sh[1][tid + off]; }
    __syncthreads();
  }
  if (tid == 0) {
    pstat[(((size_t)br * 32 + b) * 64 + c) * 2] = sh[0][0];
    pstat[(((size_t)br * 32 + b) * 64 + c) * 2 + 1] = sh[1][0];
  }
}

// ---------------- pack static conv weights into MFMA A-fragment order ----------------
__global__ __launch_bounds__(256) void pack_static_kernel(
    const float* __restrict__ wk1c1, const float* __restrict__ wk1c2,
    const float* __restrict__ wk2c1, const float* __restrict__ wk2c2,
    const float* __restrict__ wconv, _Float16* __restrict__ wpk) {
  int idx = blockIdx.x * 256 + threadIdx.x;  // 258048
  int j = idx & 7, lane = (idx >> 3) & 63;
  int tap = (idx >> 9) % 9;
  int chunk = (idx / 4608) % 14;
  int br = idx / 64512;
  int g = lane >> 4;
  int c = (j < 4) ? 4 * g + j : 16 + 4 * g + (j - 4);
  const float* src; int ol0;
  if (chunk < 2)       { src = wk1c1 + (size_t)br * 32 * 288; ol0 = chunk * 16; }
  else if (chunk < 6)  { src = wk1c2 + (size_t)br * 64 * 288; ol0 = (chunk - 2) * 16; }
  else if (chunk < 8)  { src = wk2c1 + (size_t)br * 32 * 288; ol0 = (chunk - 6) * 16; }
  else if (chunk < 12) { src = wk2c2 + (size_t)br * 64 * 288; ol0 = (chunk - 8) * 16; }
  else                 { src = wconv + (size_t)br * 32 * 288; ol0 = (chunk - 12) * 16; }
  int o = ol0 + (lane & 15);
  wpk[idx] = (_Float16)(src[((size_t)o * 32 + c) * 9 + tap]);
}

// ---------------- MFMA conv: 9 shifted K=32 GEMMs; branch via blockIdx.z ----------------
template <int MODE>
__global__ __launch_bounds__(256) void conv_mfma_kernel(
    const float* __restrict__ xin, const _Float16* __restrict__ wAll,
    const float* __restrict__ pstat, const float* __restrict__ a_pre,
    int brBase, float* __restrict__ slabBase, size_t slabStride,
    _Float16* __restrict__ vb0, size_t vstrideH) {
  const int NCHUNK = (MODE == 0) ? 14 : 4;
  int bz = blockIdx.z;
  int br = brBase + bz;
  float* slab = slabBase + (size_t)bz * slabStride;
  __shared__ _Float16 hsh[6 * 66 * 36];  // [row6][col66][c-pad36]
  __shared__ float alsh[32], besh[32];
  int tid = threadIdx.x;
  int b = blockIdx.y, r0 = blockIdx.x * 4;
  int ch0 = (br & 1) * 32;
  if (MODE == 0 && tid < 32) {  // reduce x-stats + fold bn/shortcut into affine
    float s = 0.f, s2 = 0.f;
    for (int bb = 0; bb < 32; bb++) {
      size_t p = ((size_t)bb * 64 + ch0 + tid) * 2;
      s += pstat[p]; s2 += pstat[p + 1];
    }
    const float N = 131072.f;
    float m = s / N;
    float r = rsqrtf(s2 / N - m * m + EPSV);
    alsh[tid] = 0.5f * r + 0.01f * a_pre[br];
    besh[tid] = -0.5f * m * r;
  }
  __syncthreads();
  for (int t = tid; t < 384; t += 256) {  // zero halo cols
    int row = t >> 6, colh = ((t & 63) >> 5) ? 65 : 0, c = t & 31;
    hsh[(row * 66 + colh) * 36 + c] = (_Float16)0.f;
  }
  if (MODE == 0) {
    for (int t = tid; t < 32 * 96; t += 256) {  // float4 staging + affine
      int c = t / 96, p4 = (t % 96) * 4;
      int row = p4 >> 6, col = p4 & 63;
      int rg = r0 + row - 1;
      float4 v4 = {0.f, 0.f, 0.f, 0.f};
      if ((unsigned)rg < 64u)
        v4 = *(const float4*)&xin[((size_t)b * 64 + ch0 + c) * HW + (rg << 6) + col];
      float a = alsh[c], be = besh[c];
      _Float16* dst = &hsh[((size_t)row * 66 + col + 1) * 36 + c];
      dst[0]   = (_Float16)(v4.x * a + be);
      dst[36]  = (_Float16)(v4.y * a + be);
      dst[72]  = (_Float16)(v4.z * a + be);
      dst[108] = (_Float16)(v4.w * a + be);
    }
  } else {
    const _Float16* cin = (const _Float16*)(slab + OFF_CCB);
    for (int t = tid; t < 32 * 48; t += 256) {  // 16B staging
      int c = t / 48, p8 = (t % 48) * 8;
      int row = p8 >> 6, col = p8 & 63;
      int rg = r0 + row - 1;
      H8 v; v.u4 = make_uint4(0, 0, 0, 0);
      if ((unsigned)rg < 64u)
        v.u4 = *(const uint4*)&cin[((size_t)b * 32 + c) * HW + (rg << 6) + col];
      _Float16* dst = &hsh[((size_t)row * 66 + col + 1) * 36 + c];
      #pragma unroll
      for (int k = 0; k < 8; k++) dst[36 * k] = v.v[k];
    }
  }
  __syncthreads();
  int w = tid >> 6, l = tid & 63;
  int ln = l & 15, g = l >> 4;
  H8 bfr[4][9];
  #pragma unroll
  for (int pf = 0; pf < 4; pf++)
    #pragma unroll
    for (int dyi = 0; dyi < 3; dyi++)
      #pragma unroll
      for (int dxi = 0; dxi < 3; dxi++) {
        const _Float16* p = &hsh[(((size_t)(w + dyi)) * 66 + pf * 16 + ln + dxi) * 36 + 4 * g];
        H8 f;
        f.q[0] = *(const ushort4*)p;
        f.q[1] = *(const ushort4*)(p + 16);
        bfr[pf][dyi * 3 + dxi] = f;
      }
  const _Float16* wb = (MODE == 0)
      ? wAll + (size_t)br * 64512
      : wAll + (size_t)br * 589824 + (size_t)b * 18432;
  for (int chunk = 0; chunk < NCHUNK; chunk++) {
    H8 af[9];
    #pragma unroll
    for (int t = 0; t < 9; t++)
      af[t].u4 = *(const uint4*)(wb + (((size_t)chunk * 9 + t) * 64 + l) * 8);
    _Float16* ob; int Cb, ol0;
    if (MODE == 0) {
      if (chunk < 2)       { ob = (_Float16*)(slab + OFF_Y1A); Cb = 32; ol0 = chunk * 16; }
      else if (chunk < 6)  { ob = (_Float16*)(slab + OFF_Y1B); Cb = 64; ol0 = (chunk - 2) * 16; }
      else if (chunk < 8)  { ob = (_Float16*)(slab + OFF_Y2A); Cb = 32; ol0 = (chunk - 6) * 16; }
      else if (chunk < 12) { ob = (_Float16*)(slab + OFF_Y2B); Cb = 64; ol0 = (chunk - 8) * 16; }
      else                 { ob = (_Float16*)(slab + OFF_CCB); Cb = 32; ol0 = (chunk - 12) * 16; }
    } else { ob = vb0 + (size_t)br * vstrideH; Cb = 64; ol0 = chunk * 16; }
    #pragma unroll
    for (int pf = 0; pf < 4; pf++) {
      f32x4 acc = {0.f, 0.f, 0.f, 0.f};
      #pragma unroll
      for (int t = 0; t < 9; t++)
        acc = __builtin_amdgcn_mfma_f32_16x16x32_f16(bfr[pf][t].v, af[t].v, acc, 0, 0, 0);
      union { _Float16 h[4]; ushort4 u; } sv;
      #pragma unroll
      for (int j = 0; j < 4; j++) sv.h[j] = (_Float16)acc[j];
      int px = ((r0 + w) << 6) + pf * 16 + 4 * g;
      *(ushort4*)&ob[((size_t)b * Cb + ol0 + ln) * HW + px] = sv.u;
    }
  }
}

// ---------------- attn1 MFMA: all 9 kk per block; 9 rows per block, dj-compacted LDS ----------------
// grid (7, 32, nslab); partials part1[rg][b][kk][o][i]
__global__ __launch_bounds__(256) void attn1_mfma_kernel(
    float* __restrict__ slabBase, size_t slabStride) {
  __shared__ _Float16 comp[3][96][34];  // [dj][ch 0-31=y1(i),32-95=y2(o)][q padded]
  int rg = blockIdx.x, b = blockIdx.y;
  float* slab = slabBase + (size_t)blockIdx.z * slabStride;
  const _Float16* y1 = (const _Float16*)(slab + OFF_Y1A);
  const _Float16* y2 = (const _Float16*)(slab + OFF_Y1B);
  int tid = threadIdx.x;
  for (int t = tid; t < 4896; t += 256) ((unsigned int*)comp)[t] = 0u;  // zero incl. q-pad
  int w = tid >> 6, lr = tid & 15, g = (tid >> 4) & 3;
  f32x4 acc[9][2];
  #pragma unroll
  for (int kk = 0; kk < 9; kk++) {
    acc[kk][0] = (f32x4){0.f, 0.f, 0.f, 0.f};
    acc[kk][1] = (f32x4){0.f, 0.f, 0.f, 0.f};
  }
  for (int tri = 0; tri < 3; tri++) {
    #pragma unroll
    for (int ri = 0; ri < 3; ri++) {  // di == ri (row base multiple of 3)
      int r = rg * 9 + tri * 3 + ri;
      __syncthreads();
      // stage row r, compacted by dj: each task = (ch, octet of 8 q's)
      for (int t = tid; t < 288; t += 256) {
        int ch = t / 3, oct = t % 3;
        const _Float16* src =
            (ch < 32 ? y1 + ((size_t)b * 32 + ch) * HW
                     : y2 + ((size_t)b * 64 + (ch - 32)) * HW) + (r << 6) + oct * 24;
        union { uint4 q[3]; ushort u[24]; } dat;
        dat.q[0] = *(const uint4*)(src);
        dat.q[1] = *(const uint4*)(src + 8);
        dat.q[2] = *(const uint4*)(src + 16);
        #pragma unroll
        for (int dj = 0; dj < 3; dj++) {
          union { ushort u[8]; uint4 q; } o_;
          #pragma unroll
          for (int m = 0; m < 8; m++) o_.u[m] = dat.u[dj + 3 * m];
          if (oct == 2) { o_.u[5] = 0; o_.u[6] = 0; o_.u[7] = 0; }  // q>20 invalid
          *(uint4*)&comp[dj][ch][oct * 8] = o_.q;
        }
      }
      __syncthreads();
      #pragma unroll
      for (int dj = 0; dj < 3; dj++) {
        H8 af, bf0, bf1;
        const _Float16* pa = &comp[dj][32 + 16 * w + lr][4 * g];
        af.q[0] = *(const ushort4*)pa;  af.q[1] = *(const ushort4*)(pa + 16);
        const _Float16* p0 = &comp[dj][lr][4 * g];
        bf0.q[0] = *(const ushort4*)p0; bf0.q[1] = *(const ushort4*)(p0 + 16);
        const _Float16* p1 = &comp[dj][16 + lr][4 * g];
        bf1.q[0] = *(const ushort4*)p1; bf1.q[1] = *(const ushort4*)(p1 + 16);
        acc[ri * 3 + dj][0] =
            __builtin_amdgcn_mfma_f32_16x16x32_f16(af.v, bf0.v, acc[ri * 3 + dj][0], 0, 0, 0);
        acc[ri * 3 + dj][1] =
            __builtin_amdgcn_mfma_f32_16x16x32_f16(af.v, bf1.v, acc[ri * 3 + dj][1], 0, 0, 0);
      }
    }
  }
  float* part = slab + OFF_P1;  // [rg][b][kk][o][i]
  #pragma unroll
  for (int kk = 0; kk < 9; kk++) {
    size_t base = (((size_t)rg * 32 + b) * 9 + kk) * 2048 + (16 * w + 4 * g) * 32 + lr;
    #pragma unroll
    for (int j = 0; j < 4; j++) {
      part[base + (size_t)j * 32] = acc[kk][0][j];
      part[base + (size_t)j * 32 + 16] = acc[kk][1][j];
    }
  }
}

// ---------------- attn2 MFMA: split-K over 8 pixel segments, vectorized staging ----------------
// grid (8, 32, nslab); partials part2[ps][b][o*32+i]
__global__ __launch_bounds__(256) void attn2_mfma_kernel(
    float* __restrict__ slabBase, size_t slabStride) {
  __shared__ _Float16 comp[96][68];
  int ps = blockIdx.x, b = blockIdx.y;
  float* slab = slabBase + (size_t)blockIdx.z * slabStride;
  const _Float16* y1 = (const _Float16*)(slab + OFF_Y2A);
  const _Float16* y2 = (const _Float16*)(slab + OFF_Y2B);
  int tid = threadIdx.x;
  int w = tid >> 6, lr = tid & 15, g = (tid >> 4) & 3;
  f32x4 acc0 = {0.f, 0.f, 0.f, 0.f}, acc1 = {0.f, 0.f, 0.f, 0.f};
  for (int st = 0; st < 8; st++) {
    __syncthreads();
    #pragma unroll
    for (int t0 = 0; t0 < 3; t0++) {
      int t = tid + t0 * 256;  // 768 tasks: (ch, 8px part)
      int ch = t >> 3, part = t & 7;
      const _Float16* src =
          (ch < 32 ? y1 + ((size_t)b * 32 + ch) * HW
                   : y2 + ((size_t)b * 64 + (ch - 32)) * HW) + ps * 512 + st * 64 + part * 8;
      *(uint4*)&comp[ch][part * 8] = *(const uint4*)src;
    }
    __syncthreads();
    #pragma unroll
    for (int kh = 0; kh < 2; kh++) {
      H8 af, bf0, bf1;
      const _Float16* pa = &comp[32 + 16 * w + lr][kh * 32 + 4 * g];
      af.q[0] = *(const ushort4*)pa;  af.q[1] = *(const ushort4*)(pa + 16);
      const _Float16* p0 = &comp[lr][kh * 32 + 4 * g];
      bf0.q[0] = *(const ushort4*)p0; bf0.q[1] = *(const ushort4*)(p0 + 16);
      const _Float16* p1 = &comp[16 + lr][kh * 32 + 4 * g];
      bf1.q[0] = *(const ushort4*)p1; bf1.q[1] = *(const ushort4*)(p1 + 16);
      acc0 = __builtin_amdgcn_mfma_f32_16x16x32_f16(af.v, bf0.v, acc0, 0, 0, 0);
      acc1 = __builtin_amdgcn_mfma_f32_16x16x32_f16(af.v, bf1.v, acc1, 0, 0, 0);
    }
  }
  float* p2 = slab + OFF_P2;
  size_t base = ((size_t)ps * 32 + b) * 2048 + (16 * w + 4 * g) * 32 + lr;
  #pragma unroll
  for (int j = 0; j < 4; j++) {
    p2[base + (size_t)j * 32] = acc0[j];
    p2[base + (size_t)j * 32 + 16] = acc1[j];
  }
}

// ---------------- fused: reduce partials + softmax + ak + pack ----------------
__global__ __launch_bounds__(320) void fused_ak_kernel(
    float* __restrict__ slabBase, size_t slabStride, int brBase,
    const float* __restrict__ aw, _Float16* __restrict__ wdynB) {
  int o = blockIdx.x, b = blockIdx.y;
  int bz = blockIdx.z, br = brBase + bz;
  float* slab = slabBase + (size_t)bz * slabStride;
  const float* part1 = slab + OFF_P1;
  const float* part2 = slab + OFF_P2;
  const float* awb = aw + (size_t)br * 18432;
  _Float16* wdyn = wdynB + (size_t)br * 589824;
  int tid = threadIdx.x;
  __shared__ float sm[33];
  if (tid < 32) {
    float s = 0.f;
    #pragma unroll
    for (int ps = 0; ps < 8; ps++) s += part2[((size_t)ps * 32 + b) * 2048 + o * 32 + tid];
    sm[tid] = s * 0.17677669529663687f;  // 1/sqrt(32)
  }
  __syncthreads();
  if (tid == 0) {
    float mx = -1e30f;
    for (int k = 0; k < 32; k++) mx = fmaxf(mx, sm[k]);
    float sum = 0.f;
    for (int k = 0; k < 32; k++) { float e = expf(sm[k] - mx); sm[k] = e; sum += e; }
    sm[32] = 1.0f / sum;
  }
  __syncthreads();
  if (tid < 288) {
    int i = tid / 9, kk = tid % 9;
    float a1v = 0.f;
    #pragma unroll
    for (int rg = 0; rg < 7; rg++)
      a1v += part1[(((size_t)rg * 32 + b) * 9 + kk) * 2048 + o * 32 + i];
    a1v *= 0.05892556509887896f;  // 1/sqrt(288)
    float akv = sm[i] * sm[32] * (a1v + awb[(size_t)(o * 32 + i) * 9 + kk]);
    int chunk = o >> 4;
    int g = (i & 15) >> 2;
    int j = (i & 3) + ((i >= 16) ? 4 : 0);
    int lane = (g << 4) | (o & 15);
    wdyn[((((size_t)b * 4 + chunk) * 9 + kk) * 64 + lane) * 8 + j] = (_Float16)akv;
  }
}

// ---------------- fused finalize: v-stats reduce + 4-branch combine ----------------
__global__ __launch_bounds__(256) void finalize_kernel(
    const _Float16* __restrict__ vb0, size_t vstrideH,
    const float* __restrict__ pstat, const float* __restrict__ a_post,
    const float* __restrict__ x, const float* __restrict__ cm,
    float* __restrict__ out) {
  __shared__ float sga[256], sgb[256];
  int t = threadIdx.x;
  {
    int br = t >> 6, o = t & 63;
    float s = 0.f, s2 = 0.f;
    for (int bb = 0; bb < 32; bb++) {
      size_t p = (((size_t)br * 32 + bb) * 64 + o) * 2;
      s += pstat[p]; s2 += pstat[p + 1];
    }
    const float N = 131072.f;
    float m = s / N;
    float r = rsqrtf(s2 / N - m * m + EPSV);
    sga[t] = 0.5f * r + 0.6f * a_post[br];
    sgb[t] = -0.5f * m * r;
  }
  __syncthreads();
  size_t g8 = ((size_t)blockIdx.x * 256 + threadIdx.x) * 8;
  int o = (int)((g8 >> 12) & 63);
  float acc[8], ysv[8];
  #pragma unroll
  for (int br = 0; br < 4; br++) {
    float ga = sga[br * 64 + o], gb = sgb[br * 64 + o];
    H8 v; v.u4 = *(const uint4*)(vb0 + (size_t)br * vstrideH + g8);
    #pragma unroll
    for (int j = 0; j < 8; j++) {
      float y = ga * (float)v.v[j] + gb;
      if (br == 0) acc[j] = y;
      else if (br == 1) acc[j] += y;
      else if (br == 2) ysv[j] = y;
      else acc[j] += ysv[j] * y;
    }
  }
  float cmv = 0.99f * cm[0];
  const float4* xp = (const float4*)(x + g8);
  float4 x0 = xp[0], x1 = xp[1];
  float4 o0, o1;
  o0.x = cmv * x0.x + acc[0] * 0.5773502691896258f;
  o0.y = cmv * x0.y + acc[1] * 0.5773502691896258f;
  o0.z = cmv * x0.z + acc[2] * 0.5773502691896258f;
  o0.w = cmv * x0.w + acc[3] * 0.5773502691896258f;
  o1.x = cmv * x1.x + acc[4] * 0.5773502691896258f;
  o1.y = cmv * x1.y + acc[5] * 0.5773502691896258f;
  o1.z = cmv * x1.z + acc[6] * 0.5773502691896258f;
  o1.w = cmv * x1.w + acc[7] * 0.5773502691896258f;
  float4* op = (float4*)(out + g8);
  op[0] = o0;
  op[1] = o1;
}

extern "C" void kernel_launch(void* const* d_in, const int* in_sizes, int n_in,
                              void* d_out, int out_size, void* d_ws, size_t ws_size,
                              hipStream_t stream) {
  const float* x      = (const float*)d_in[0];
  const float* wk1c1  = (const float*)d_in[1];
  const float* wk1c2  = (const float*)d_in[2];
  const float* wk2c1  = (const float*)d_in[3];
  const float* wk2c2  = (const float*)d_in[4];
  const float* wconv  = (const float*)d_in[5];
  const float* attn_w = (const float*)d_in[6];
  const float* a_pre  = (const float*)d_in[7];
  const float* a_post = (const float*)d_in[8];
  const float* cm     = (const float*)d_in[9];
  float* out = (float*)d_out;

  const size_t FIX_F = 129024ull + 1179648ull + 16384ull;  // wpk + wdyn + pstat
  const size_t needB = (4 * SLAB_F + FIX_F) * 4;
  bool batched = ws_size >= needB;
  size_t nslab = batched ? 4 : 1;

  float* ws = (float*)d_ws;
  float* slab0 = ws;
  float* fixF  = ws + nslab * SLAB_F;
  _Float16* wpk   = (_Float16*)fixF;
  _Float16* wdynB = (_Float16*)(fixF + 129024);
  float* pstat    = fixF + 129024 + 1179648;
  _Float16* vb0;
  size_t vstrideH;
  if (batched) { vb0 = (_Float16*)(slab0 + OFF_P1); vstrideH = SLAB_F * 2; }
  else         { vb0 = (_Float16*)(fixF + FIX_F);   vstrideH = 8388608; }

  size_t SS = batched ? SLAB_F : 0;

  bn_partial_kernel<<<dim3(64, 32), 256, 0, stream>>>(x, pstat);
  pack_static_kernel<<<1008, 256, 0, stream>>>(wk1c1, wk1c2, wk2c1, wk2c2, wconv, wpk);

  if (batched) {
    conv_mfma_kernel<0><<<dim3(16, 32, 4), 256, 0, stream>>>(
        x, wpk, pstat, a_pre, 0, slab0, SS, nullptr, 0);
    attn1_mfma_kernel<<<dim3(7, 32, 4), 256, 0, stream>>>(slab0, SS);
    attn2_mfma_kernel<<<dim3(8, 32, 4), 256, 0, stream>>>(slab0, SS);
    fused_ak_kernel<<<dim3(64, 32, 4), 320, 0, stream>>>(slab0, SS, 0, attn_w, wdynB);
    conv_mfma_kernel<1><<<dim3(16, 32, 4), 256, 0, stream>>>(
        nullptr, wdynB, nullptr, nullptr, 0, slab0, SS, vb0, vstrideH);
  } else {
    for (int br = 0; br < 4; br++) {
      conv_mfma_kernel<0><<<dim3(16, 32, 1), 256, 0, stream>>>(
          x, wpk, pstat, a_pre, br, slab0, 0, nullptr, 0);
      attn1_mfma_kernel<<<dim3(7, 32, 1), 256, 0, stream>>>(slab0, 0);
      attn2_mfma_kernel<<<dim3(8, 32, 1), 256, 0, stream>>>(slab0, 0);
      fused_ak_kernel<<<dim3(64, 32, 1), 320, 0, stream>>>(slab0, 0, br, attn_w, wdynB);
      conv_mfma_kernel<1><<<dim3(16, 32, 1), 256, 0, stream>>>(
          nullptr, wdynB, nullptr, nullptr, br, slab0, 0, vb0, vstrideH);
    }
  }

  bnv_partial_kernel<<<dim3(64, 32, 4), 256, 0, stream>>>(vb0, vstrideH, pstat);
  finalize_kernel<<<4096, 256, 0, stream>>>(vb0, vstrideH, pstat, a_post, x, cm, out);
}

// Round 14
// 373.240 us; speedup vs baseline: 1.4685x; 1.1806x over previous
//
#include <hip/hip_runtime.h>
#include <math.h>

#define HW 4096
#define EPSV 1e-5f

typedef _Float16 half8 __attribute__((ext_vector_type(8)));
typedef float f32x4 __attribute__((ext_vector_type(4)));
union H8 { half8 v; ushort4 q[2]; uint4 u4; };

// slab layout (float offsets) — R12-proven layout, 23,068,672 floats/slab
#define SLAB_F 23068672ull
#define OFF_Y1A 0
#define OFF_Y2A 2097152
#define OFF_Y1B 4194304
#define OFF_Y2B 8388608
#define OFF_CCB 12582912
#define OFF_P1  14680064   // a1 partials [rg7][b][kk][o][i] = 4,128,768 f32
#define OFF_P2  18874368   // part2 [ps8][b][o*32+i] = 524,288 f32

// ---------------- bn stats over x: one (b,c) plane per block, float4 ----------------
__global__ __launch_bounds__(256) void bn_partial_kernel(
    const float* __restrict__ x, float* __restrict__ pstat) {
  int c = blockIdx.x, b = blockIdx.y;
  int tid = threadIdx.x;
  const float4* p = (const float4*)(x + ((size_t)b * 64 + c) * HW);
  float sm = 0.f, s2 = 0.f;
  #pragma unroll
  for (int i = 0; i < 4; i++) {
    float4 v = p[tid + i * 256];
    sm += v.x + v.y + v.z + v.w;
    s2 += v.x * v.x + v.y * v.y + v.z * v.z + v.w * v.w;
  }
  __shared__ float sh[2][256];
  sh[0][tid] = sm; sh[1][tid] = s2;
  __syncthreads();
  for (int off = 128; off > 0; off >>= 1) {
    if (tid < off) { sh[0][tid] += sh[0][tid + off]; sh[1][tid] += sh[1][tid + off]; }
    __syncthreads();
  }
  if (tid == 0) {
    pstat[((size_t)b * 64 + c) * 2] = sh[0][0];
    pstat[((size_t)b * 64 + c) * 2 + 1] = sh[1][0];
  }
}

// ---------------- bn stats over v (f16): one (br,b,c) plane per block ----------------
__global__ __launch_bounds__(256) void bnv_partial_kernel(
    const _Float16* __restrict__ vb0, size_t vstrideH, float* __restrict__ pstat) {
  int c = blockIdx.x, b = blockIdx.y, br = blockIdx.z;
  int tid = threadIdx.x;
  const _Float16* row = vb0 + (size_t)br * vstrideH + ((size_t)b * 64 + c) * HW;
  float sm = 0.f, s2 = 0.f;
  #pragma unroll
  for (int i = 0; i < 2; i++) {
    H8 v; v.u4 = *(const uint4*)(row + (tid + i * 256) * 8);
    #pragma unroll
    for (int k = 0; k < 8; k++) { float t = (float)v.v[k]; sm += t; s2 += t * t; }
  }
  __shared__ float sh[2][256];
  sh[0][tid] = sm; sh[1][tid] = s2;
  __syncthreads();
  for (int off = 128; off > 0; off >>= 1) {
    if (tid < off) { sh[0][tid] += sh[0][tid + off]; sh[1][tid] += sh[1][tid + off]; }
    __syncthreads();
  }
  if (tid == 0) {
    pstat[(((size_t)br * 32 + b) * 64 + c) * 2] = sh[0][0];
    pstat[(((size_t)br * 32 + b) * 64 + c) * 2 + 1] = sh[1][0];
  }
}

// ---------------- pack static conv weights into MFMA A-fragment order ----------------
__global__ __launch_bounds__(256) void pack_static_kernel(
    const float* __restrict__ wk1c1, const float* __restrict__ wk1c2,
    const float* __restrict__ wk2c1, const float* __restrict__ wk2c2,
    const float* __restrict__ wconv, _Float16* __restrict__ wpk) {
  int idx = blockIdx.x * 256 + threadIdx.x;  // 258048
  int j = idx & 7, lane = (idx >> 3) & 63;
  int tap = (idx >> 9) % 9;
  int chunk = (idx / 4608) % 14;
  int br = idx / 64512;
  int g = lane >> 4;
  int c = (j < 4) ? 4 * g + j : 16 + 4 * g + (j - 4);
  const float* src; int ol0;
  if (chunk < 2)       { src = wk1c1 + (size_t)br * 32 * 288; ol0 = chunk * 16; }
  else if (chunk < 6)  { src = wk1c2 + (size_t)br * 64 * 288; ol0 = (chunk - 2) * 16; }
  else if (chunk < 8)  { src = wk2c1 + (size_t)br * 32 * 288; ol0 = (chunk - 6) * 16; }
  else if (chunk < 12) { src = wk2c2 + (size_t)br * 64 * 288; ol0 = (chunk - 8) * 16; }
  else                 { src = wconv + (size_t)br * 32 * 288; ol0 = (chunk - 12) * 16; }
  int o = ol0 + (lane & 15);
  wpk[idx] = (_Float16)(src[((size_t)o * 32 + c) * 9 + tap]);
}

// ---------------- MFMA conv: 9 shifted K=32 GEMMs; branch via blockIdx.z ----------------
template <int MODE>
__global__ __launch_bounds__(256) void conv_mfma_kernel(
    const float* __restrict__ xin, const _Float16* __restrict__ wAll,
    const float* __restrict__ pstat, const float* __restrict__ a_pre,
    int brBase, float* __restrict__ slabBase, size_t slabStride,
    _Float16* __restrict__ vb0, size_t vstrideH) {
  const int NCHUNK = (MODE == 0) ? 14 : 4;
  int bz = blockIdx.z;
  int br = brBase + bz;
  float* slab = slabBase + (size_t)bz * slabStride;
  __shared__ _Float16 hsh[6 * 66 * 36];  // [row6][col66][c-pad36]
  __shared__ float alsh[32], besh[32];
  int tid = threadIdx.x;
  int b = blockIdx.y, r0 = blockIdx.x * 4;
  int ch0 = (br & 1) * 32;
  if (MODE == 0 && tid < 32) {  // reduce x-stats + fold bn/shortcut into affine
    float s = 0.f, s2 = 0.f;
    for (int bb = 0; bb < 32; bb++) {
      size_t p = ((size_t)bb * 64 + ch0 + tid) * 2;
      s += pstat[p]; s2 += pstat[p + 1];
    }
    const float N = 131072.f;
    float m = s / N;
    float r = rsqrtf(s2 / N - m * m + EPSV);
    alsh[tid] = 0.5f * r + 0.01f * a_pre[br];
    besh[tid] = -0.5f * m * r;
  }
  __syncthreads();
  for (int t = tid; t < 384; t += 256) {  // zero halo cols
    int row = t >> 6, colh = ((t & 63) >> 5) ? 65 : 0, c = t & 31;
    hsh[(row * 66 + colh) * 36 + c] = (_Float16)0.f;
  }
  if (MODE == 0) {
    for (int t = tid; t < 32 * 96; t += 256) {  // float4 staging + affine
      int c = t / 96, p4 = (t % 96) * 4;
      int row = p4 >> 6, col = p4 & 63;
      int rg = r0 + row - 1;
      float4 v4 = {0.f, 0.f, 0.f, 0.f};
      if ((unsigned)rg < 64u)
        v4 = *(const float4*)&xin[((size_t)b * 64 + ch0 + c) * HW + (rg << 6) + col];
      float a = alsh[c], be = besh[c];
      _Float16* dst = &hsh[((size_t)row * 66 + col + 1) * 36 + c];
      dst[0]   = (_Float16)(v4.x * a + be);
      dst[36]  = (_Float16)(v4.y * a + be);
      dst[72]  = (_Float16)(v4.z * a + be);
      dst[108] = (_Float16)(v4.w * a + be);
    }
  } else {
    const _Float16* cin = (const _Float16*)(slab + OFF_CCB);
    for (int t = tid; t < 32 * 48; t += 256) {  // 16B staging
      int c = t / 48, p8 = (t % 48) * 8;
      int row = p8 >> 6, col = p8 & 63;
      int rg = r0 + row - 1;
      H8 v; v.u4 = make_uint4(0, 0, 0, 0);
      if ((unsigned)rg < 64u)
        v.u4 = *(const uint4*)&cin[((size_t)b * 32 + c) * HW + (rg << 6) + col];
      _Float16* dst = &hsh[((size_t)row * 66 + col + 1) * 36 + c];
      #pragma unroll
      for (int k = 0; k < 8; k++) dst[36 * k] = v.v[k];
    }
  }
  __syncthreads();
  int w = tid >> 6, l = tid & 63;
  int ln = l & 15, g = l >> 4;
  H8 bfr[4][9];
  #pragma unroll
  for (int pf = 0; pf < 4; pf++)
    #pragma unroll
    for (int dyi = 0; dyi < 3; dyi++)
      #pragma unroll
      for (int dxi = 0; dxi < 3; dxi++) {
        const _Float16* p = &hsh[(((size_t)(w + dyi)) * 66 + pf * 16 + ln + dxi) * 36 + 4 * g];
        H8 f;
        f.q[0] = *(const ushort4*)p;
        f.q[1] = *(const ushort4*)(p + 16);
        bfr[pf][dyi * 3 + dxi] = f;
      }
  const _Float16* wb = (MODE == 0)
      ? wAll + (size_t)br * 64512
      : wAll + (size_t)br * 589824 + (size_t)b * 18432;
  for (int chunk = 0; chunk < NCHUNK; chunk++) {
    H8 af[9];
    #pragma unroll
    for (int t = 0; t < 9; t++)
      af[t].u4 = *(const uint4*)(wb + (((size_t)chunk * 9 + t) * 64 + l) * 8);
    _Float16* ob; int Cb, ol0;
    if (MODE == 0) {
      if (chunk < 2)       { ob = (_Float16*)(slab + OFF_Y1A); Cb = 32; ol0 = chunk * 16; }
      else if (chunk < 6)  { ob = (_Float16*)(slab + OFF_Y1B); Cb = 64; ol0 = (chunk - 2) * 16; }
      else if (chunk < 8)  { ob = (_Float16*)(slab + OFF_Y2A); Cb = 32; ol0 = (chunk - 6) * 16; }
      else if (chunk < 12) { ob = (_Float16*)(slab + OFF_Y2B); Cb = 64; ol0 = (chunk - 8) * 16; }
      else                 { ob = (_Float16*)(slab + OFF_CCB); Cb = 32; ol0 = (chunk - 12) * 16; }
    } else { ob = vb0 + (size_t)br * vstrideH; Cb = 64; ol0 = chunk * 16; }
    #pragma unroll
    for (int pf = 0; pf < 4; pf++) {
      f32x4 acc = {0.f, 0.f, 0.f, 0.f};
      #pragma unroll
      for (int t = 0; t < 9; t++)
        acc = __builtin_amdgcn_mfma_f32_16x16x32_f16(bfr[pf][t].v, af[t].v, acc, 0, 0, 0);
      union { _Float16 h[4]; ushort4 u; } sv;
      #pragma unroll
      for (int j = 0; j < 4; j++) sv.h[j] = (_Float16)acc[j];
      int px = ((r0 + w) << 6) + pf * 16 + 4 * g;
      *(ushort4*)&ob[((size_t)b * Cb + ol0 + ln) * HW + px] = sv.u;
    }
  }
}

// ---------------- attn1 MFMA: all 9 kk per block; 9 rows per block, dj-compacted LDS ----------------
// grid (7, 32, nslab); partials part1[rg][b][kk][o][i]
__global__ __launch_bounds__(256) void attn1_mfma_kernel(
    float* __restrict__ slabBase, size_t slabStride) {
  __shared__ _Float16 comp[3][96][34];  // [dj][ch 0-31=y1(i),32-95=y2(o)][q padded]
  int rg = blockIdx.x, b = blockIdx.y;
  float* slab = slabBase + (size_t)blockIdx.z * slabStride;
  const _Float16* y1 = (const _Float16*)(slab + OFF_Y1A);
  const _Float16* y2 = (const _Float16*)(slab + OFF_Y1B);
  int tid = threadIdx.x;
  for (int t = tid; t < 4896; t += 256) ((unsigned int*)comp)[t] = 0u;  // zero incl. q-pad
  int w = tid >> 6, lr = tid & 15, g = (tid >> 4) & 3;
  f32x4 acc[9][2];
  #pragma unroll
  for (int kk = 0; kk < 9; kk++) {
    acc[kk][0] = (f32x4){0.f, 0.f, 0.f, 0.f};
    acc[kk][1] = (f32x4){0.f, 0.f, 0.f, 0.f};
  }
  for (int tri = 0; tri < 3; tri++) {
    #pragma unroll
    for (int ri = 0; ri < 3; ri++) {  // di == ri (row base multiple of 3)
      int r = rg * 9 + tri * 3 + ri;
      __syncthreads();
      // stage row r, compacted by dj: each task = (ch, octet of 8 q's)
      for (int t = tid; t < 288; t += 256) {
        int ch = t / 3, oct = t % 3;
        const _Float16* src =
            (ch < 32 ? y1 + ((size_t)b * 32 + ch) * HW
                     : y2 + ((size_t)b * 64 + (ch - 32)) * HW) + (r << 6) + oct * 24;
        union { uint4 q[3]; ushort u[24]; } dat;
        dat.q[0] = *(const uint4*)(src);
        dat.q[1] = *(const uint4*)(src + 8);
        dat.q[2] = *(const uint4*)(src + 16);
        #pragma unroll
        for (int dj = 0; dj < 3; dj++) {
          union { ushort u[8]; uint4 q; } o_;
          #pragma unroll
          for (int m = 0; m < 8; m++) o_.u[m] = dat.u[dj + 3 * m];
          if (oct == 2) { o_.u[5] = 0; o_.u[6] = 0; o_.u[7] = 0; }  // q>20 invalid
          *(uint4*)&comp[dj][ch][oct * 8] = o_.q;
        }
      }
      __syncthreads();
      #pragma unroll
      for (int dj = 0; dj < 3; dj++) {
        H8 af, bf0, bf1;
        const _Float16* pa = &comp[dj][32 + 16 * w + lr][4 * g];
        af.q[0] = *(const ushort4*)pa;  af.q[1] = *(const ushort4*)(pa + 16);
        const _Float16* p0 = &comp[dj][lr][4 * g];
        bf0.q[0] = *(const ushort4*)p0; bf0.q[1] = *(const ushort4*)(p0 + 16);
        const _Float16* p1 = &comp[dj][16 + lr][4 * g];
        bf1.q[0] = *(const ushort4*)p1; bf1.q[1] = *(const ushort4*)(p1 + 16);
        acc[ri * 3 + dj][0] =
            __builtin_amdgcn_mfma_f32_16x16x32_f16(af.v, bf0.v, acc[ri * 3 + dj][0], 0, 0, 0);
        acc[ri * 3 + dj][1] =
            __builtin_amdgcn_mfma_f32_16x16x32_f16(af.v, bf1.v, acc[ri * 3 + dj][1], 0, 0, 0);
      }
    }
  }
  float* part = slab + OFF_P1;  // [rg][b][kk][o][i]
  #pragma unroll
  for (int kk = 0; kk < 9; kk++) {
    size_t base = (((size_t)rg * 32 + b) * 9 + kk) * 2048 + (16 * w + 4 * g) * 32 + lr;
    #pragma unroll
    for (int j = 0; j < 4; j++) {
      part[base + (size_t)j * 32] = acc[kk][0][j];
      part[base + (size_t)j * 32 + 16] = acc[kk][1][j];
    }
  }
}

// ---------------- attn2 MFMA: split-K over 8 pixel segments, vectorized staging ----------------
// grid (8, 32, nslab); partials part2[ps][b][o*32+i]
__global__ __launch_bounds__(256) void attn2_mfma_kernel(
    float* __restrict__ slabBase, size_t slabStride) {
  __shared__ _Float16 comp[96][68];
  int ps = blockIdx.x, b = blockIdx.y;
  float* slab = slabBase + (size_t)blockIdx.z * slabStride;
  const _Float16* y1 = (const _Float16*)(slab + OFF_Y2A);
  const _Float16* y2 = (const _Float16*)(slab + OFF_Y2B);
  int tid = threadIdx.x;
  int w = tid >> 6, lr = tid & 15, g = (tid >> 4) & 3;
  f32x4 acc0 = {0.f, 0.f, 0.f, 0.f}, acc1 = {0.f, 0.f, 0.f, 0.f};
  for (int st = 0; st < 8; st++) {
    __syncthreads();
    #pragma unroll
    for (int t0 = 0; t0 < 3; t0++) {
      int t = tid + t0 * 256;  // 768 tasks: (ch, 8px part)
      int ch = t >> 3, part = t & 7;
      const _Float16* src =
          (ch < 32 ? y1 + ((size_t)b * 32 + ch) * HW
                   : y2 + ((size_t)b * 64 + (ch - 32)) * HW) + ps * 512 + st * 64 + part * 8;
      *(uint4*)&comp[ch][part * 8] = *(const uint4*)src;
    }
    __syncthreads();
    #pragma unroll
    for (int kh = 0; kh < 2; kh++) {
      H8 af, bf0, bf1;
      const _Float16* pa = &comp[32 + 16 * w + lr][kh * 32 + 4 * g];
      af.q[0] = *(const ushort4*)pa;  af.q[1] = *(const ushort4*)(pa + 16);
      const _Float16* p0 = &comp[lr][kh * 32 + 4 * g];
      bf0.q[0] = *(const ushort4*)p0; bf0.q[1] = *(const ushort4*)(p0 + 16);
      const _Float16* p1 = &comp[16 + lr][kh * 32 + 4 * g];
      bf1.q[0] = *(const ushort4*)p1; bf1.q[1] = *(const ushort4*)(p1 + 16);
      acc0 = __builtin_amdgcn_mfma_f32_16x16x32_f16(af.v, bf0.v, acc0, 0, 0, 0);
      acc1 = __builtin_amdgcn_mfma_f32_16x16x32_f16(af.v, bf1.v, acc1, 0, 0, 0);
    }
  }
  float* p2 = slab + OFF_P2;
  size_t base = ((size_t)ps * 32 + b) * 2048 + (16 * w + 4 * g) * 32 + lr;
  #pragma unroll
  for (int j = 0; j < 4; j++) {
    p2[base + (size_t)j * 32] = acc0[j];
    p2[base + (size_t)j * 32 + 16] = acc1[j];
  }
}

// ---------------- fused: reduce partials + softmax + ak + pack ----------------
__global__ __launch_bounds__(320) void fused_ak_kernel(
    float* __restrict__ slabBase, size_t slabStride, int brBase,
    const float* __restrict__ aw, _Float16* __restrict__ wdynB) {
  int o = blockIdx.x, b = blockIdx.y;
  int bz = blockIdx.z, br = brBase + bz;
  float* slab = slabBase + (size_t)bz * slabStride;
  const float* part1 = slab + OFF_P1;
  const float* part2 = slab + OFF_P2;
  const float* awb = aw + (size_t)br * 18432;
  _Float16* wdyn = wdynB + (size_t)br * 589824;
  int tid = threadIdx.x;
  __shared__ float sm[33];
  if (tid < 32) {
    float s = 0.f;
    #pragma unroll
    for (int ps = 0; ps < 8; ps++) s += part2[((size_t)ps * 32 + b) * 2048 + o * 32 + tid];
    sm[tid] = s * 0.17677669529663687f;  // 1/sqrt(32)
  }
  __syncthreads();
  if (tid == 0) {
    float mx = -1e30f;
    for (int k = 0; k < 32; k++) mx = fmaxf(mx, sm[k]);
    float sum = 0.f;
    for (int k = 0; k < 32; k++) { float e = expf(sm[k] - mx); sm[k] = e; sum += e; }
    sm[32] = 1.0f / sum;
  }
  __syncthreads();
  if (tid < 288) {
    int i = tid / 9, kk = tid % 9;
    float a1v = 0.f;
    #pragma unroll
    for (int rg = 0; rg < 7; rg++)
      a1v += part1[(((size_t)rg * 32 + b) * 9 + kk) * 2048 + o * 32 + i];
    a1v *= 0.05892556509887896f;  // 1/sqrt(288)
    float akv = sm[i] * sm[32] * (a1v + awb[(size_t)(o * 32 + i) * 9 + kk]);
    int chunk = o >> 4;
    int g = (i & 15) >> 2;
    int j = (i & 3) + ((i >= 16) ? 4 : 0);
    int lane = (g << 4) | (o & 15);
    wdyn[((((size_t)b * 4 + chunk) * 9 + kk) * 64 + lane) * 8 + j] = (_Float16)akv;
  }
}

// ---------------- fused finalize: v-stats reduce + 4-branch combine ----------------
__global__ __launch_bounds__(256) void finalize_kernel(
    const _Float16* __restrict__ vb0, size_t vstrideH,
    const float* __restrict__ pstat, const float* __restrict__ a_post,
    const float* __restrict__ x, const float* __restrict__ cm,
    float* __restrict__ out) {
  __shared__ float sga[256], sgb[256];
  int t = threadIdx.x;
  {
    int br = t >> 6, o = t & 63;
    float s = 0.f, s2 = 0.f;
    for (int bb = 0; bb < 32; bb++) {
      size_t p = (((size_t)br * 32 + bb) * 64 + o) * 2;
      s += pstat[p]; s2 += pstat[p + 1];
    }
    const float N = 131072.f;
    float m = s / N;
    float r = rsqrtf(s2 / N - m * m + EPSV);
    sga[t] = 0.5f * r + 0.6f * a_post[br];
    sgb[t] = -0.5f * m * r;
  }
  __syncthreads();
  size_t g8 = ((size_t)blockIdx.x * 256 + threadIdx.x) * 8;
  int o = (int)((g8 >> 12) & 63);
  float acc[8], ysv[8];
  #pragma unroll
  for (int br = 0; br < 4; br++) {
    float ga = sga[br * 64 + o], gb = sgb[br * 64 + o];
    H8 v; v.u4 = *(const uint4*)(vb0 + (size_t)br * vstrideH + g8);
    #pragma unroll
    for (int j = 0; j < 8; j++) {
      float y = ga * (float)v.v[j] + gb;
      if (br == 0) acc[j] = y;
      else if (br == 1) acc[j] += y;
      else if (br == 2) ysv[j] = y;
      else acc[j] += ysv[j] * y;
    }
  }
  float cmv = 0.99f * cm[0];
  const float4* xp = (const float4*)(x + g8);
  float4 x0 = xp[0], x1 = xp[1];
  float4 o0, o1;
  o0.x = cmv * x0.x + acc[0] * 0.5773502691896258f;
  o0.y = cmv * x0.y + acc[1] * 0.5773502691896258f;
  o0.z = cmv * x0.z + acc[2] * 0.5773502691896258f;
  o0.w = cmv * x0.w + acc[3] * 0.5773502691896258f;
  o1.x = cmv * x1.x + acc[4] * 0.5773502691896258f;
  o1.y = cmv * x1.y + acc[5] * 0.5773502691896258f;
  o1.z = cmv * x1.z + acc[6] * 0.5773502691896258f;
  o1.w = cmv * x1.w + acc[7] * 0.5773502691896258f;
  float4* op = (float4*)(out + g8);
  op[0] = o0;
  op[1] = o1;
}

extern "C" void kernel_launch(void* const* d_in, const int* in_sizes, int n_in,
                              void* d_out, int out_size, void* d_ws, size_t ws_size,
                              hipStream_t stream) {
  const float* x      = (const float*)d_in[0];
  const float* wk1c1  = (const float*)d_in[1];
  const float* wk1c2  = (const float*)d_in[2];
  const float* wk2c1  = (const float*)d_in[3];
  const float* wk2c2  = (const float*)d_in[4];
  const float* wconv  = (const float*)d_in[5];
  const float* attn_w = (const float*)d_in[6];
  const float* a_pre  = (const float*)d_in[7];
  const float* a_post = (const float*)d_in[8];
  const float* cm     = (const float*)d_in[9];
  float* out = (float*)d_out;

  const size_t VBUF_F = 16777216ull;                      // 4 branches of v (f16)
  const size_t FIX_F  = 129024ull + 1179648ull + 16384ull; // wpk + wdyn + pstat
  size_t wsF = ws_size / 4;
  int nslab = (wsF >= 2 * SLAB_F + FIX_F + VBUF_F) ? 2 : 1;

  float* ws = (float*)d_ws;
  float* slab0 = ws;
  float* fixF  = ws + (size_t)nslab * SLAB_F;
  _Float16* wpk   = (_Float16*)fixF;
  _Float16* wdynB = (_Float16*)(fixF + 129024);
  float* pstat    = fixF + 129024 + 1179648;   // x-stats first, v-stats later (after passes)
  _Float16* vb0   = (_Float16*)(fixF + FIX_F); // dedicated vbuf region, never aliased
  const size_t VSH = 8388608ull;               // vbuf branch stride in f16

  bn_partial_kernel<<<dim3(64, 32), 256, 0, stream>>>(x, pstat);
  pack_static_kernel<<<1008, 256, 0, stream>>>(wk1c1, wk1c2, wk2c1, wk2c2, wconv, wpk);

  for (int b0 = 0; b0 < 4; b0 += nslab) {
    conv_mfma_kernel<0><<<dim3(16, 32, nslab), 256, 0, stream>>>(
        x, wpk, pstat, a_pre, b0, slab0, SLAB_F, nullptr, 0);
    attn1_mfma_kernel<<<dim3(7, 32, nslab), 256, 0, stream>>>(slab0, SLAB_F);
    attn2_mfma_kernel<<<dim3(8, 32, nslab), 256, 0, stream>>>(slab0, SLAB_F);
    fused_ak_kernel<<<dim3(64, 32, nslab), 320, 0, stream>>>(
        slab0, SLAB_F, b0, attn_w, wdynB);
    conv_mfma_kernel<1><<<dim3(16, 32, nslab), 256, 0, stream>>>(
        nullptr, wdynB, nullptr, nullptr, b0, slab0, SLAB_F, vb0, VSH);
  }

  bnv_partial_kernel<<<dim3(64, 32, 4), 256, 0, stream>>>(vb0, VSH, pstat);
  finalize_kernel<<<4096, 256, 0, stream>>>(vb0, VSH, pstat, a_post, x, cm, out);
}

// Round 15
// 356.234 us; speedup vs baseline: 1.5386x; 1.0477x over previous
//
#include <hip/hip_runtime.h>
#include <math.h>

#define HW 4096
#define EPSV 1e-5f

typedef _Float16 half8 __attribute__((ext_vector_type(8)));
typedef float f32x4 __attribute__((ext_vector_type(4)));
union H8 { half8 v; ushort4 q[2]; uint4 u4; };

// slab layout (float offsets) — lifetime-aliased, 15,204,352 floats/slab
//   y1a [0, 2.10M)        -> dead after attn1; conv<1> writes vbuf here (4-slab path)
//   y1b [2.10M, 6.29M)
//   y2a [6.29M, 8.39M)    -> dead after attn2
//   y2b [8.39M, 12.58M)   -> dead after attn2
//   ccb [12.58M, 14.68M)
//   P2  [14.68M, 15.20M)
//   P1 = y2a base (4.13M over dead y2a/y2b; attn2 runs BEFORE attn1)
#define SLAB_F  15204352ull
#define OFF_Y1A 0
#define OFF_Y1B 2097152
#define OFF_Y2A 6291456
#define OFF_Y2B 8388608
#define OFF_CCB 12582912
#define OFF_P2  14680064
#define OFF_P1  6291456

// ---------------- bn stats over x: one (b,c) plane per block, float4 ----------------
__global__ __launch_bounds__(256) void bn_partial_kernel(
    const float* __restrict__ x, float* __restrict__ pstat) {
  int c = blockIdx.x, b = blockIdx.y;
  int tid = threadIdx.x;
  const float4* p = (const float4*)(x + ((size_t)b * 64 + c) * HW);
  float sm = 0.f, s2 = 0.f;
  #pragma unroll
  for (int i = 0; i < 4; i++) {
    float4 v = p[tid + i * 256];
    sm += v.x + v.y + v.z + v.w;
    s2 += v.x * v.x + v.y * v.y + v.z * v.z + v.w * v.w;
  }
  __shared__ float sh[2][256];
  sh[0][tid] = sm; sh[1][tid] = s2;
  __syncthreads();
  for (int off = 128; off > 0; off >>= 1) {
    if (tid < off) { sh[0][tid] += sh[0][tid + off]; sh[1][tid] += sh[1][tid + off]; }
    __syncthreads();
  }
  if (tid == 0) {
    pstat[((size_t)b * 64 + c) * 2] = sh[0][0];
    pstat[((size_t)b * 64 + c) * 2 + 1] = sh[1][0];
  }
}

// ---------------- bn stats over v (f16): one (br,b,c) plane per block ----------------
__global__ __launch_bounds__(256) void bnv_partial_kernel(
    const _Float16* __restrict__ vb0, size_t vstrideH, float* __restrict__ pstat) {
  int c = blockIdx.x, b = blockIdx.y, br = blockIdx.z;
  int tid = threadIdx.x;
  const _Float16* row = vb0 + (size_t)br * vstrideH + ((size_t)b * 64 + c) * HW;
  float sm = 0.f, s2 = 0.f;
  #pragma unroll
  for (int i = 0; i < 2; i++) {
    H8 v; v.u4 = *(const uint4*)(row + (tid + i * 256) * 8);
    #pragma unroll
    for (int k = 0; k < 8; k++) { float t = (float)v.v[k]; sm += t; s2 += t * t; }
  }
  __shared__ float sh[2][256];
  sh[0][tid] = sm; sh[1][tid] = s2;
  __syncthreads();
  for (int off = 128; off > 0; off >>= 1) {
    if (tid < off) { sh[0][tid] += sh[0][tid + off]; sh[1][tid] += sh[1][tid + off]; }
    __syncthreads();
  }
  if (tid == 0) {
    pstat[(((size_t)br * 32 + b) * 64 + c) * 2] = sh[0][0];
    pstat[(((size_t)br * 32 + b) * 64 + c) * 2 + 1] = sh[1][0];
  }
}

// ---------------- pack static conv weights into MFMA A-fragment order ----------------
__global__ __launch_bounds__(256) void pack_static_kernel(
    const float* __restrict__ wk1c1, const float* __restrict__ wk1c2,
    const float* __restrict__ wk2c1, const float* __restrict__ wk2c2,
    const float* __restrict__ wconv, _Float16* __restrict__ wpk) {
  int idx = blockIdx.x * 256 + threadIdx.x;  // 258048
  int j = idx & 7, lane = (idx >> 3) & 63;
  int tap = (idx >> 9) % 9;
  int chunk = (idx / 4608) % 14;
  int br = idx / 64512;
  int g = lane >> 4;
  int c = (j < 4) ? 4 * g + j : 16 + 4 * g + (j - 4);
  const float* src; int ol0;
  if (chunk < 2)       { src = wk1c1 + (size_t)br * 32 * 288; ol0 = chunk * 16; }
  else if (chunk < 6)  { src = wk1c2 + (size_t)br * 64 * 288; ol0 = (chunk - 2) * 16; }
  else if (chunk < 8)  { src = wk2c1 + (size_t)br * 32 * 288; ol0 = (chunk - 6) * 16; }
  else if (chunk < 12) { src = wk2c2 + (size_t)br * 64 * 288; ol0 = (chunk - 8) * 16; }
  else                 { src = wconv + (size_t)br * 32 * 288; ol0 = (chunk - 12) * 16; }
  int o = ol0 + (lane & 15);
  wpk[idx] = (_Float16)(src[((size_t)o * 32 + c) * 9 + tap]);
}

// ---------------- MFMA conv: 9 shifted K=32 GEMMs; branch via blockIdx.z ----------------
template <int MODE>
__global__ __launch_bounds__(256) void conv_mfma_kernel(
    const float* __restrict__ xin, const _Float16* __restrict__ wAll,
    const float* __restrict__ pstat, const float* __restrict__ a_pre,
    int brBase, float* __restrict__ slabBase, size_t slabStride,
    _Float16* __restrict__ vb0, size_t vstrideH) {
  const int NCHUNK = (MODE == 0) ? 14 : 4;
  int bz = blockIdx.z;
  int br = brBase + bz;
  float* slab = slabBase + (size_t)bz * slabStride;
  __shared__ _Float16 hsh[6 * 66 * 36];  // [row6][col66][c-pad36]
  __shared__ float alsh[32], besh[32];
  int tid = threadIdx.x;
  int b = blockIdx.y, r0 = blockIdx.x * 4;
  int ch0 = (br & 1) * 32;
  if (MODE == 0 && tid < 32) {  // reduce x-stats + fold bn/shortcut into affine
    float s = 0.f, s2 = 0.f;
    for (int bb = 0; bb < 32; bb++) {
      size_t p = ((size_t)bb * 64 + ch0 + tid) * 2;
      s += pstat[p]; s2 += pstat[p + 1];
    }
    const float N = 131072.f;
    float m = s / N;
    float r = rsqrtf(s2 / N - m * m + EPSV);
    alsh[tid] = 0.5f * r + 0.01f * a_pre[br];
    besh[tid] = -0.5f * m * r;
  }
  __syncthreads();
  for (int t = tid; t < 384; t += 256) {  // zero halo cols
    int row = t >> 6, colh = ((t & 63) >> 5) ? 65 : 0, c = t & 31;
    hsh[(row * 66 + colh) * 36 + c] = (_Float16)0.f;
  }
  if (MODE == 0) {
    for (int t = tid; t < 32 * 96; t += 256) {  // float4 staging + affine
      int c = t / 96, p4 = (t % 96) * 4;
      int row = p4 >> 6, col = p4 & 63;
      int rg = r0 + row - 1;
      float4 v4 = {0.f, 0.f, 0.f, 0.f};
      if ((unsigned)rg < 64u)
        v4 = *(const float4*)&xin[((size_t)b * 64 + ch0 + c) * HW + (rg << 6) + col];
      float a = alsh[c], be = besh[c];
      _Float16* dst = &hsh[((size_t)row * 66 + col + 1) * 36 + c];
      dst[0]   = (_Float16)(v4.x * a + be);
      dst[36]  = (_Float16)(v4.y * a + be);
      dst[72]  = (_Float16)(v4.z * a + be);
      dst[108] = (_Float16)(v4.w * a + be);
    }
  } else {
    const _Float16* cin = (const _Float16*)(slab + OFF_CCB);
    for (int t = tid; t < 32 * 48; t += 256) {  // 16B staging
      int c = t / 48, p8 = (t % 48) * 8;
      int row = p8 >> 6, col = p8 & 63;
      int rg = r0 + row - 1;
      H8 v; v.u4 = make_uint4(0, 0, 0, 0);
      if ((unsigned)rg < 64u)
        v.u4 = *(const uint4*)&cin[((size_t)b * 32 + c) * HW + (rg << 6) + col];
      _Float16* dst = &hsh[((size_t)row * 66 + col + 1) * 36 + c];
      #pragma unroll
      for (int k = 0; k < 8; k++) dst[36 * k] = v.v[k];
    }
  }
  __syncthreads();
  int w = tid >> 6, l = tid & 63;
  int ln = l & 15, g = l >> 4;
  H8 bfr[4][9];
  #pragma unroll
  for (int pf = 0; pf < 4; pf++)
    #pragma unroll
    for (int dyi = 0; dyi < 3; dyi++)
      #pragma unroll
      for (int dxi = 0; dxi < 3; dxi++) {
        const _Float16* p = &hsh[(((size_t)(w + dyi)) * 66 + pf * 16 + ln + dxi) * 36 + 4 * g];
        H8 f;
        f.q[0] = *(const ushort4*)p;
        f.q[1] = *(const ushort4*)(p + 16);
        bfr[pf][dyi * 3 + dxi] = f;
      }
  const _Float16* wb = (MODE == 0)
      ? wAll + (size_t)br * 64512
      : wAll + (size_t)br * 589824 + (size_t)b * 18432;
  for (int chunk = 0; chunk < NCHUNK; chunk++) {
    H8 af[9];
    #pragma unroll
    for (int t = 0; t < 9; t++)
      af[t].u4 = *(const uint4*)(wb + (((size_t)chunk * 9 + t) * 64 + l) * 8);
    _Float16* ob; int Cb, ol0;
    if (MODE == 0) {
      if (chunk < 2)       { ob = (_Float16*)(slab + OFF_Y1A); Cb = 32; ol0 = chunk * 16; }
      else if (chunk < 6)  { ob = (_Float16*)(slab + OFF_Y1B); Cb = 64; ol0 = (chunk - 2) * 16; }
      else if (chunk < 8)  { ob = (_Float16*)(slab + OFF_Y2A); Cb = 32; ol0 = (chunk - 6) * 16; }
      else if (chunk < 12) { ob = (_Float16*)(slab + OFF_Y2B); Cb = 64; ol0 = (chunk - 8) * 16; }
      else                 { ob = (_Float16*)(slab + OFF_CCB); Cb = 32; ol0 = (chunk - 12) * 16; }
    } else { ob = vb0 + (size_t)br * vstrideH; Cb = 64; ol0 = chunk * 16; }
    #pragma unroll
    for (int pf = 0; pf < 4; pf++) {
      f32x4 acc = {0.f, 0.f, 0.f, 0.f};
      #pragma unroll
      for (int t = 0; t < 9; t++)
        acc = __builtin_amdgcn_mfma_f32_16x16x32_f16(bfr[pf][t].v, af[t].v, acc, 0, 0, 0);
      union { _Float16 h[4]; ushort4 u; } sv;
      #pragma unroll
      for (int j = 0; j < 4; j++) sv.h[j] = (_Float16)acc[j];
      int px = ((r0 + w) << 6) + pf * 16 + 4 * g;
      *(ushort4*)&ob[((size_t)b * Cb + ol0 + ln) * HW + px] = sv.u;
    }
  }
}

// ---------------- attn1 MFMA: all 9 kk per block; 9 rows per block, dj-compacted LDS ----------------
// grid (7, 32, nslab); partials part1[rg][b][kk][o][i]  (P1 aliases dead y2a/y2b)
__global__ __launch_bounds__(256) void attn1_mfma_kernel(
    float* __restrict__ slabBase, size_t slabStride) {
  __shared__ _Float16 comp[3][96][34];  // [dj][ch 0-31=y1(i),32-95=y2(o)][q padded]
  int rg = blockIdx.x, b = blockIdx.y;
  float* slab = slabBase + (size_t)blockIdx.z * slabStride;
  const _Float16* y1 = (const _Float16*)(slab + OFF_Y1A);
  const _Float16* y2 = (const _Float16*)(slab + OFF_Y1B);
  int tid = threadIdx.x;
  for (int t = tid; t < 4896; t += 256) ((unsigned int*)comp)[t] = 0u;  // zero incl. q-pad
  int w = tid >> 6, lr = tid & 15, g = (tid >> 4) & 3;
  f32x4 acc[9][2];
  #pragma unroll
  for (int kk = 0; kk < 9; kk++) {
    acc[kk][0] = (f32x4){0.f, 0.f, 0.f, 0.f};
    acc[kk][1] = (f32x4){0.f, 0.f, 0.f, 0.f};
  }
  for (int tri = 0; tri < 3; tri++) {
    #pragma unroll
    for (int ri = 0; ri < 3; ri++) {  // di == ri (row base multiple of 3)
      int r = rg * 9 + tri * 3 + ri;
      __syncthreads();
      // stage row r, compacted by dj: each task = (ch, octet of 8 q's)
      for (int t = tid; t < 288; t += 256) {
        int ch = t / 3, oct = t % 3;
        const _Float16* src =
            (ch < 32 ? y1 + ((size_t)b * 32 + ch) * HW
                     : y2 + ((size_t)b * 64 + (ch - 32)) * HW) + (r << 6) + oct * 24;
        union { uint4 q[3]; ushort u[24]; } dat;
        dat.q[0] = *(const uint4*)(src);
        dat.q[1] = *(const uint4*)(src + 8);
        dat.q[2] = *(const uint4*)(src + 16);
        #pragma unroll
        for (int dj = 0; dj < 3; dj++) {
          union { ushort u[8]; uint4 q; } o_;
          #pragma unroll
          for (int m = 0; m < 8; m++) o_.u[m] = dat.u[dj + 3 * m];
          if (oct == 2) { o_.u[5] = 0; o_.u[6] = 0; o_.u[7] = 0; }  // q>20 invalid
          *(uint4*)&comp[dj][ch][oct * 8] = o_.q;
        }
      }
      __syncthreads();
      #pragma unroll
      for (int dj = 0; dj < 3; dj++) {
        H8 af, bf0, bf1;
        const _Float16* pa = &comp[dj][32 + 16 * w + lr][4 * g];
        af.q[0] = *(const ushort4*)pa;  af.q[1] = *(const ushort4*)(pa + 16);
        const _Float16* p0 = &comp[dj][lr][4 * g];
        bf0.q[0] = *(const ushort4*)p0; bf0.q[1] = *(const ushort4*)(p0 + 16);
        const _Float16* p1 = &comp[dj][16 + lr][4 * g];
        bf1.q[0] = *(const ushort4*)p1; bf1.q[1] = *(const ushort4*)(p1 + 16);
        acc[ri * 3 + dj][0] =
            __builtin_amdgcn_mfma_f32_16x16x32_f16(af.v, bf0.v, acc[ri * 3 + dj][0], 0, 0, 0);
        acc[ri * 3 + dj][1] =
            __builtin_amdgcn_mfma_f32_16x16x32_f16(af.v, bf1.v, acc[ri * 3 + dj][1], 0, 0, 0);
      }
    }
  }
  float* part = slab + OFF_P1;  // [rg][b][kk][o][i]
  #pragma unroll
  for (int kk = 0; kk < 9; kk++) {
    size_t base = (((size_t)rg * 32 + b) * 9 + kk) * 2048 + (16 * w + 4 * g) * 32 + lr;
    #pragma unroll
    for (int j = 0; j < 4; j++) {
      part[base + (size_t)j * 32] = acc[kk][0][j];
      part[base + (size_t)j * 32 + 16] = acc[kk][1][j];
    }
  }
}

// ---------------- attn2 MFMA: split-K over 8 pixel segments, vectorized staging ----------------
// grid (8, 32, nslab); partials part2[ps][b][o*32+i]   (runs BEFORE attn1)
__global__ __launch_bounds__(256) void attn2_mfma_kernel(
    float* __restrict__ slabBase, size_t slabStride) {
  __shared__ _Float16 comp[96][68];
  int ps = blockIdx.x, b = blockIdx.y;
  float* slab = slabBase + (size_t)blockIdx.z * slabStride;
  const _Float16* y1 = (const _Float16*)(slab + OFF_Y2A);
  const _Float16* y2 = (const _Float16*)(slab + OFF_Y2B);
  int tid = threadIdx.x;
  int w = tid >> 6, lr = tid & 15, g = (tid >> 4) & 3;
  f32x4 acc0 = {0.f, 0.f, 0.f, 0.f}, acc1 = {0.f, 0.f, 0.f, 0.f};
  for (int st = 0; st < 8; st++) {
    __syncthreads();
    #pragma unroll
    for (int t0 = 0; t0 < 3; t0++) {
      int t = tid + t0 * 256;  // 768 tasks: (ch, 8px part)
      int ch = t >> 3, part = t & 7;
      const _Float16* src =
          (ch < 32 ? y1 + ((size_t)b * 32 + ch) * HW
                   : y2 + ((size_t)b * 64 + (ch - 32)) * HW) + ps * 512 + st * 64 + part * 8;
      *(uint4*)&comp[ch][part * 8] = *(const uint4*)src;
    }
    __syncthreads();
    #pragma unroll
    for (int kh = 0; kh < 2; kh++) {
      H8 af, bf0, bf1;
      const _Float16* pa = &comp[32 + 16 * w + lr][kh * 32 + 4 * g];
      af.q[0] = *(const ushort4*)pa;  af.q[1] = *(const ushort4*)(pa + 16);
      const _Float16* p0 = &comp[lr][kh * 32 + 4 * g];
      bf0.q[0] = *(const ushort4*)p0; bf0.q[1] = *(const ushort4*)(p0 + 16);
      const _Float16* p1 = &comp[16 + lr][kh * 32 + 4 * g];
      bf1.q[0] = *(const ushort4*)p1; bf1.q[1] = *(const ushort4*)(p1 + 16);
      acc0 = __builtin_amdgcn_mfma_f32_16x16x32_f16(af.v, bf0.v, acc0, 0, 0, 0);
      acc1 = __builtin_amdgcn_mfma_f32_16x16x32_f16(af.v, bf1.v, acc1, 0, 0, 0);
    }
  }
  float* p2 = slab + OFF_P2;
  size_t base = ((size_t)ps * 32 + b) * 2048 + (16 * w + 4 * g) * 32 + lr;
  #pragma unroll
  for (int j = 0; j < 4; j++) {
    p2[base + (size_t)j * 32] = acc0[j];
    p2[base + (size_t)j * 32 + 16] = acc1[j];
  }
}

// ---------------- fused: reduce partials + softmax + ak + pack ----------------
__global__ __launch_bounds__(320) void fused_ak_kernel(
    float* __restrict__ slabBase, size_t slabStride, int brBase,
    const float* __restrict__ aw, _Float16* __restrict__ wdynB) {
  int o = blockIdx.x, b = blockIdx.y;
  int bz = blockIdx.z, br = brBase + bz;
  float* slab = slabBase + (size_t)bz * slabStride;
  const float* part1 = slab + OFF_P1;
  const float* part2 = slab + OFF_P2;
  const float* awb = aw + (size_t)br * 18432;
  _Float16* wdyn = wdynB + (size_t)br * 589824;
  int tid = threadIdx.x;
  __shared__ float sm[33];
  if (tid < 32) {
    float s = 0.f;
    #pragma unroll
    for (int ps = 0; ps < 8; ps++) s += part2[((size_t)ps * 32 + b) * 2048 + o * 32 + tid];
    sm[tid] = s * 0.17677669529663687f;  // 1/sqrt(32)
  }
  __syncthreads();
  if (tid == 0) {
    float mx = -1e30f;
    for (int k = 0; k < 32; k++) mx = fmaxf(mx, sm[k]);
    float sum = 0.f;
    for (int k = 0; k < 32; k++) { float e = expf(sm[k] - mx); sm[k] = e; sum += e; }
    sm[32] = 1.0f / sum;
  }
  __syncthreads();
  if (tid < 288) {
    int i = tid / 9, kk = tid % 9;
    float a1v = 0.f;
    #pragma unroll
    for (int rg = 0; rg < 7; rg++)
      a1v += part1[(((size_t)rg * 32 + b) * 9 + kk) * 2048 + o * 32 + i];
    a1v *= 0.05892556509887896f;  // 1/sqrt(288)
    float akv = sm[i] * sm[32] * (a1v + awb[(size_t)(o * 32 + i) * 9 + kk]);
    int chunk = o >> 4;
    int g = (i & 15) >> 2;
    int j = (i & 3) + ((i >= 16) ? 4 : 0);
    int lane = (g << 4) | (o & 15);
    wdyn[((((size_t)b * 4 + chunk) * 9 + kk) * 64 + lane) * 8 + j] = (_Float16)akv;
  }
}

// ---------------- fused finalize: v-stats reduce + 4-branch combine ----------------
__global__ __launch_bounds__(256) void finalize_kernel(
    const _Float16* __restrict__ vb0, size_t vstrideH,
    const float* __restrict__ pstat, const float* __restrict__ a_post,
    const float* __restrict__ x, const float* __restrict__ cm,
    float* __restrict__ out) {
  __shared__ float sga[256], sgb[256];
  int t = threadIdx.x;
  {
    int br = t >> 6, o = t & 63;
    float s = 0.f, s2 = 0.f;
    for (int bb = 0; bb < 32; bb++) {
      size_t p = (((size_t)br * 32 + bb) * 64 + o) * 2;
      s += pstat[p]; s2 += pstat[p + 1];
    }
    const float N = 131072.f;
    float m = s / N;
    float r = rsqrtf(s2 / N - m * m + EPSV);
    sga[t] = 0.5f * r + 0.6f * a_post[br];
    sgb[t] = -0.5f * m * r;
  }
  __syncthreads();
  size_t g8 = ((size_t)blockIdx.x * 256 + threadIdx.x) * 8;
  int o = (int)((g8 >> 12) & 63);
  float acc[8], ysv[8];
  #pragma unroll
  for (int br = 0; br < 4; br++) {
    float ga = sga[br * 64 + o], gb = sgb[br * 64 + o];
    H8 v; v.u4 = *(const uint4*)(vb0 + (size_t)br * vstrideH + g8);
    #pragma unroll
    for (int j = 0; j < 8; j++) {
      float y = ga * (float)v.v[j] + gb;
      if (br == 0) acc[j] = y;
      else if (br == 1) acc[j] += y;
      else if (br == 2) ysv[j] = y;
      else acc[j] += ysv[j] * y;
    }
  }
  float cmv = 0.99f * cm[0];
  const float4* xp = (const float4*)(x + g8);
  float4 x0 = xp[0], x1 = xp[1];
  float4 o0, o1;
  o0.x = cmv * x0.x + acc[0] * 0.5773502691896258f;
  o0.y = cmv * x0.y + acc[1] * 0.5773502691896258f;
  o0.z = cmv * x0.z + acc[2] * 0.5773502691896258f;
  o0.w = cmv * x0.w + acc[3] * 0.5773502691896258f;
  o1.x = cmv * x1.x + acc[4] * 0.5773502691896258f;
  o1.y = cmv * x1.y + acc[5] * 0.5773502691896258f;
  o1.z = cmv * x1.z + acc[6] * 0.5773502691896258f;
  o1.w = cmv * x1.w + acc[7] * 0.5773502691896258f;
  float4* op = (float4*)(out + g8);
  op[0] = o0;
  op[1] = o1;
}

extern "C" void kernel_launch(void* const* d_in, const int* in_sizes, int n_in,
                              void* d_out, int out_size, void* d_ws, size_t ws_size,
                              hipStream_t stream) {
  const float* x      = (const float*)d_in[0];
  const float* wk1c1  = (const float*)d_in[1];
  const float* wk1c2  = (const float*)d_in[2];
  const float* wk2c1  = (const float*)d_in[3];
  const float* wk2c2  = (const float*)d_in[4];
  const float* wconv  = (const float*)d_in[5];
  const float* attn_w = (const float*)d_in[6];
  const float* a_pre  = (const float*)d_in[7];
  const float* a_post = (const float*)d_in[8];
  const float* cm     = (const float*)d_in[9];
  float* out = (float*)d_out;

  const size_t FIX_F  = 129024ull + 1179648ull + 16384ull;  // wpk + wdyn + pstat
  const size_t VBUF_F = 16777216ull;                        // fallback-only dedicated vbuf
  size_t wsF = ws_size / 4;
  int nslab;
  if (wsF >= 4 * SLAB_F + FIX_F) nslab = 4;
  else if (wsF >= 2 * SLAB_F + FIX_F + VBUF_F) nslab = 2;
  else nslab = 1;

  float* ws = (float*)d_ws;
  float* slab0 = ws;
  float* fixF  = ws + (size_t)nslab * SLAB_F;
  _Float16* wpk   = (_Float16*)fixF;
  _Float16* wdynB = (_Float16*)(fixF + 129024);
  float* pstat    = fixF + 129024 + 1179648;
  // vbuf: 4-slab path aliases each slab's dead y1a region; fallback uses dedicated region
  _Float16* vb0;
  size_t VSH;
  if (nslab == 4) { vb0 = (_Float16*)(slab0 + OFF_Y1A); VSH = SLAB_F * 2; }
  else            { vb0 = (_Float16*)(fixF + FIX_F);    VSH = 8388608ull; }

  bn_partial_kernel<<<dim3(64, 32), 256, 0, stream>>>(x, pstat);
  pack_static_kernel<<<1008, 256, 0, stream>>>(wk1c1, wk1c2, wk2c1, wk2c2, wconv, wpk);

  for (int b0 = 0; b0 < 4; b0 += nslab) {
    conv_mfma_kernel<0><<<dim3(16, 32, nslab), 256, 0, stream>>>(
        x, wpk, pstat, a_pre, b0, slab0, SLAB_F, nullptr, 0);
    // attn2 first: frees y2a/y2b so attn1's P1 (aliasing them) is safe
    attn2_mfma_kernel<<<dim3(8, 32, nslab), 256, 0, stream>>>(slab0, SLAB_F);
    attn1_mfma_kernel<<<dim3(7, 32, nslab), 256, 0, stream>>>(slab0, SLAB_F);
    fused_ak_kernel<<<dim3(64, 32, nslab), 320, 0, stream>>>(
        slab0, SLAB_F, b0, attn_w, wdynB);
    conv_mfma_kernel<1><<<dim3(16, 32, nslab), 256, 0, stream>>>(
        nullptr, wdynB, nullptr, nullptr, b0, slab0, SLAB_F, vb0, VSH);
  }

  bnv_partial_kernel<<<dim3(64, 32, 4), 256, 0, stream>>>(vb0, VSH, pstat);
  finalize_kernel<<<4096, 256, 0, stream>>>(vb0, VSH, pstat, a_post, x, cm, out);
}